// Round 1
// 2701.066 us; speedup vs baseline: 1.7558x; 1.7558x over previous
//
#include <hip/hip_runtime.h>

// ConsciousTransformer forward. Round 3: MoE expert MLPs moved from per-token
// scalar VALU kernels (8 GB weight re-read per dispatch, ~585-40000 us) to
// expert-grouped bf16 MFMA GEMMs (gathered-A for mlp1, segment-contiguous mlp2).
// Dims: C=512, V=32000, L=2, P=2, E=8, HM=1024, H=8, M=256, B=2, T=1024, N=B*T=2048

#define NTOK 2048
#define CDIM 512
#define TLEN 1024
#define NB 2
#define NH 8
#define VDIM 32000

typedef __attribute__((ext_vector_type(4))) float f32x4;
typedef __attribute__((ext_vector_type(8))) __bf16 bf16x8;

#define AS1 __attribute__((address_space(1)))
#define AS3 __attribute__((address_space(3)))

__device__ __forceinline__ void g2lds16(const void* g, void* l) {
    __builtin_amdgcn_global_load_lds((const AS1 void*)g, (AS3 void*)l, 16, 0, 0);
}

// ---------------- bf16 MFMA GEMM: C = res + alpha*act(A@B^T + bias) ----------------
// A [M,K] bf16 packed, B [N,K] bf16 packed, C [M,N] fp32 (ldc).
// act: 0=none, 1=silu, 2=tanh. M,N mult of 128; K mult of 32.
__global__ __launch_bounds__(256) void gemm_bf16(
    const __bf16* __restrict__ A,
    const __bf16* __restrict__ B,
    float* __restrict__ C_, int ldc,
    const float* __restrict__ bias,
    const float* __restrict__ res, int ldres, float alpha,
    int K, int act)
{
    __shared__ __bf16 As[128 * 32];
    __shared__ __bf16 Bs[128 * 32];
    const int tid = threadIdx.x;
    const int w = tid >> 6, lane = tid & 63;
    const int m0 = blockIdx.y * 128, n0 = blockIdx.x * 128;
    const int wr = (w >> 1) * 64, wc = (w & 1) * 64;
    f32x4 acc[4][4] = {};
    const int mrow = lane & 15, kq = (lane >> 4) * 8;
    for (int k0 = 0; k0 < K; k0 += 32) {
#pragma unroll
        for (int i = 0; i < 2; ++i) {
            const int boff = w * 2048 + i * 1024 + lane * 16; // byte off in 128x32 bf16 tile
            const int row = boff >> 6;        // 64 B per row
            const int ke = (boff & 63) >> 1;  // bf16 elem within row
            g2lds16(A + (long)(m0 + row) * K + k0 + ke, (char*)As + (boff - lane * 16));
            g2lds16(B + (long)(n0 + row) * K + k0 + ke, (char*)Bs + (boff - lane * 16));
        }
        __syncthreads();
        bf16x8 af[4], bfr[4];
#pragma unroll
        for (int i = 0; i < 4; ++i)
            af[i] = *(const bf16x8*)(As + (wr + i * 16 + mrow) * 32 + kq);
#pragma unroll
        for (int j = 0; j < 4; ++j)
            bfr[j] = *(const bf16x8*)(Bs + (wc + j * 16 + mrow) * 32 + kq);
#pragma unroll
        for (int i = 0; i < 4; ++i)
#pragma unroll
            for (int j = 0; j < 4; ++j)
                acc[i][j] = __builtin_amdgcn_mfma_f32_16x16x32_bf16(af[i], bfr[j], acc[i][j], 0, 0, 0);
        __syncthreads();
    }
    const int col_l = lane & 15, row_l = (lane >> 4) * 4;
#pragma unroll
    for (int i = 0; i < 4; ++i)
#pragma unroll
        for (int j = 0; j < 4; ++j) {
            const int n = n0 + wc + j * 16 + col_l;
            const float bv = bias ? bias[n] : 0.f;
#pragma unroll
            for (int r = 0; r < 4; ++r) {
                const int m = m0 + wr + i * 16 + row_l + r;
                float v = acc[i][j][r] + bv;
                if (act == 1) v = v / (1.f + __expf(-v));
                else if (act == 2) v = tanhf(v);
                v *= alpha;
                if (res) v += res[(long)m * ldres + n];
                C_[(long)m * ldc + n] = v;
            }
        }
}

// ---------------- MoE routing: per-expert 128-aligned segments ----------------
// eidx [N,2] expert ids. Outputs: offi[0..8] segment starts (offi[8]=total rows),
// list[g] = slot id (n*2+s) for gathered row g (padding -> slot 0),
// posmap[n*2+s] = g.
__global__ __launch_bounds__(256) void route_k(const int* __restrict__ eidx,
                                               int* __restrict__ offi,
                                               int* __restrict__ list,
                                               int* __restrict__ posmap)
{
    __shared__ int cnt[8], fill[8], seg[9];
    const int t = threadIdx.x;
    if (t < 8) cnt[t] = 0;
    __syncthreads();
    for (int i = t; i < NTOK * 2; i += 256) atomicAdd(&cnt[eidx[i]], 1);
    __syncthreads();
    if (t == 0) {
        int run = 0;
        for (int e = 0; e < 8; ++e) {
            seg[e] = run;
            run += (cnt[e] + 127) & ~127;
        }
        seg[8] = run;
    }
    __syncthreads();
    if (t < 8) fill[t] = seg[t];
    if (t < 9) offi[t] = seg[t];
    __syncthreads();
    for (int i = t; i < NTOK * 2; i += 256) {
        const int e = eidx[i];
        const int g = atomicAdd(&fill[e], 1);
        list[g] = i;
        posmap[i] = g;
    }
    __syncthreads();
    // pad each segment tail with sentinel slot 0 (token 0) so GEMM reads are valid
#pragma unroll
    for (int e = 0; e < 8; ++e)
        for (int g = seg[e] + cnt[e] + t; g < seg[e + 1]; g += 256) list[g] = 0;
}

// ---------------- MoE mlp1: gathered-A GEMM + swiglu, bf16 out ----------------
// A = XNB [NTOK,512] bf16; Bw = per-expert ew1^T [1024,512] bf16; out EHB [g,1024] bf16.
__global__ __launch_bounds__(256) void moe_g1_k(
    const __bf16* __restrict__ A,
    const __bf16* __restrict__ Bw,
    const float* __restrict__ eb1l,
    const int* __restrict__ offi,
    const int* __restrict__ list,
    __bf16* __restrict__ EHB)
{
    const int m0 = blockIdx.y * 128;
    if (m0 >= offi[8]) return;
    int e = 0;
    while (e < 7 && offi[e + 1] <= m0) ++e;   // segments are 128-aligned
    const __bf16* B = Bw + (long)e * (1024 * 512);
    const float* bias = eb1l + e * 1024;
    __shared__ __bf16 As[128 * 32];
    __shared__ __bf16 Bs[128 * 32];
    __shared__ int toks[128];
    const int tid = threadIdx.x;
    if (tid < 128) toks[tid] = list[m0 + tid] >> 1;
    __syncthreads();
    const int w = tid >> 6, lane = tid & 63;
    const int n0 = blockIdx.x * 128;
    const int wr = (w >> 1) * 64, wc = (w & 1) * 64;
    f32x4 acc[4][4] = {};
    const int mrow = lane & 15, kq = (lane >> 4) * 8;
    for (int k0 = 0; k0 < 512; k0 += 32) {
#pragma unroll
        for (int i = 0; i < 2; ++i) {
            const int boff = w * 2048 + i * 1024 + lane * 16;
            const int row = boff >> 6;
            const int ke = (boff & 63) >> 1;
            g2lds16(A + (long)toks[row] * 512 + k0 + ke, (char*)As + (boff - lane * 16));
            g2lds16(B + (long)(n0 + row) * 512 + k0 + ke, (char*)Bs + (boff - lane * 16));
        }
        __syncthreads();
        bf16x8 af[4], bfr[4];
#pragma unroll
        for (int i = 0; i < 4; ++i)
            af[i] = *(const bf16x8*)(As + (wr + i * 16 + mrow) * 32 + kq);
#pragma unroll
        for (int j = 0; j < 4; ++j)
            bfr[j] = *(const bf16x8*)(Bs + (wc + j * 16 + mrow) * 32 + kq);
#pragma unroll
        for (int i = 0; i < 4; ++i)
#pragma unroll
            for (int j = 0; j < 4; ++j)
                acc[i][j] = __builtin_amdgcn_mfma_f32_16x16x32_bf16(af[i], bfr[j], acc[i][j], 0, 0, 0);
        __syncthreads();
    }
    const int col_l = lane & 15, row_l = (lane >> 4) * 4;
#pragma unroll
    for (int i = 0; i < 4; ++i)
#pragma unroll
        for (int j = 0; j < 4; ++j) {
            const int n = n0 + wc + j * 16 + col_l;
            const float bv = bias[n];
#pragma unroll
            for (int r = 0; r < 4; ++r) {
                const int g = m0 + wr + i * 16 + row_l + r;
                const float v = acc[i][j][r] + bv;
                EHB[(long)g * 1024 + n] = (__bf16)(v * v / (1.f + __expf(-v)));
            }
        }
}

// ---------------- MoE mlp2: segment-contiguous GEMM, f32 out ----------------
// A = EHB [g,1024] bf16; Bw = per-expert ew2^T [512,1024] bf16; out EYS [g,512] f32.
__global__ __launch_bounds__(256) void moe_g2_k(
    const __bf16* __restrict__ A,
    const __bf16* __restrict__ Bw,
    const float* __restrict__ eb2l,
    const int* __restrict__ offi,
    float* __restrict__ EYS)
{
    const int m0 = blockIdx.y * 128;
    if (m0 >= offi[8]) return;
    int e = 0;
    while (e < 7 && offi[e + 1] <= m0) ++e;
    const __bf16* B = Bw + (long)e * (512 * 1024);
    const float* bias = eb2l + e * 512;
    __shared__ __bf16 As[128 * 32];
    __shared__ __bf16 Bs[128 * 32];
    const int tid = threadIdx.x;
    const int w = tid >> 6, lane = tid & 63;
    const int n0 = blockIdx.x * 128;
    const int wr = (w >> 1) * 64, wc = (w & 1) * 64;
    f32x4 acc[4][4] = {};
    const int mrow = lane & 15, kq = (lane >> 4) * 8;
    for (int k0 = 0; k0 < 1024; k0 += 32) {
#pragma unroll
        for (int i = 0; i < 2; ++i) {
            const int boff = w * 2048 + i * 1024 + lane * 16;
            const int row = boff >> 6;
            const int ke = (boff & 63) >> 1;
            g2lds16(A + (long)(m0 + row) * 1024 + k0 + ke, (char*)As + (boff - lane * 16));
            g2lds16(B + (long)(n0 + row) * 1024 + k0 + ke, (char*)Bs + (boff - lane * 16));
        }
        __syncthreads();
        bf16x8 af[4], bfr[4];
#pragma unroll
        for (int i = 0; i < 4; ++i)
            af[i] = *(const bf16x8*)(As + (wr + i * 16 + mrow) * 32 + kq);
#pragma unroll
        for (int j = 0; j < 4; ++j)
            bfr[j] = *(const bf16x8*)(Bs + (wc + j * 16 + mrow) * 32 + kq);
#pragma unroll
        for (int i = 0; i < 4; ++i)
#pragma unroll
            for (int j = 0; j < 4; ++j)
                acc[i][j] = __builtin_amdgcn_mfma_f32_16x16x32_bf16(af[i], bfr[j], acc[i][j], 0, 0, 0);
        __syncthreads();
    }
    const int col_l = lane & 15, row_l = (lane >> 4) * 4;
#pragma unroll
    for (int i = 0; i < 4; ++i)
#pragma unroll
        for (int j = 0; j < 4; ++j) {
            const int n = n0 + wc + j * 16 + col_l;
            const float bv = bias[n];
#pragma unroll
            for (int r = 0; r < 4; ++r) {
                const int g = m0 + wr + i * 16 + row_l + r;
                EYS[(long)g * 512 + n] = acc[i][j][r] + bv;
            }
        }
}

// ---------------- reason = xn + 0.5*(w0*ey[pos0] + w1*ey[pos1]) ----------------
__global__ __launch_bounds__(256) void reason2_k(const float* __restrict__ xn,
                                                 const float* __restrict__ EYS,
                                                 const float* __restrict__ wv,
                                                 const int* __restrict__ posmap,
                                                 float* __restrict__ reason)
{
    const long i = (long)blockIdx.x * 256 + threadIdx.x;
    const long n = i >> 9;
    const int c = (int)(i & 511);
    const int g0 = posmap[n * 2], g1 = posmap[n * 2 + 1];
    const float v = wv[n * 2] * EYS[(long)g0 * 512 + c] + wv[n * 2 + 1] * EYS[(long)g1 * 512 + c];
    reason[i] = xn[i] + 0.5f * v;
}

// ---------------- weight transpose+convert: W [K,N] f32 -> Wt [N,K] bf16 ----------------
__global__ __launch_bounds__(256) void wtrans_k(const float* __restrict__ W,
                                                __bf16* __restrict__ Wt, int K, int N)
{
    __shared__ float tile[64][65];
    const int k0 = blockIdx.y * 64, n0 = blockIdx.x * 64;
    const int t = threadIdx.x;
#pragma unroll
    for (int i = 0; i < 4; ++i) {
        const int r = (t >> 4) + i * 16;
        const int c = (t & 15) * 4;
        float4 v = *(const float4*)(W + (long)(k0 + r) * N + n0 + c);
        tile[r][c] = v.x; tile[r][c + 1] = v.y; tile[r][c + 2] = v.z; tile[r][c + 3] = v.w;
    }
    __syncthreads();
#pragma unroll
    for (int i = 0; i < 4; ++i) {
        const int rr = (t >> 4) + i * 16;   // n
        const int cc = (t & 15) * 4;        // k
        __bf16* o = Wt + (long)(n0 + rr) * K + k0 + cc;
        o[0] = (__bf16)tile[cc][rr];
        o[1] = (__bf16)tile[cc + 1][rr];
        o[2] = (__bf16)tile[cc + 2][rr];
        o[3] = (__bf16)tile[cc + 3][rr];
    }
}

// ---------------- activation convert: src [M,lda] f32 (first K cols) -> dst [M,K] bf16 ----------------
__global__ __launch_bounds__(256) void cvta_k(const float* __restrict__ src, int lda, int K,
                                              __bf16* __restrict__ dst)
{
    const int row = blockIdx.x, t = threadIdx.x;
    const float* s = src + (long)row * lda;
    __bf16* d = dst + (long)row * K;
    for (int c = t * 4; c < K; c += 1024) {
        float4 v = *(const float4*)(s + c);
        d[c] = (__bf16)v.x; d[c + 1] = (__bf16)v.y; d[c + 2] = (__bf16)v.z; d[c + 3] = (__bf16)v.w;
    }
}

// ---------------- embedding gather ----------------
__global__ __launch_bounds__(256) void embed_k(const int* __restrict__ ids,
                                               const float* __restrict__ ew,
                                               float* __restrict__ x)
{
    const int n = blockIdx.x, t = threadIdx.x;
    const long r = (long)ids[n] * CDIM;
    x[(long)n * CDIM + t]       = ew[r + t];
    x[(long)n * CDIM + 256 + t] = ew[r + 256 + t];
}

// ---------------- row softmax (width 256), in place ----------------
__global__ __launch_bounds__(256) void smrows_k(float* __restrict__ a)
{
    const int n = blockIdx.x, t = threadIdx.x;
    __shared__ float rs[256];
    float v = a[(long)n * 256 + t];
    rs[t] = v; __syncthreads();
    for (int o = 128; o; o >>= 1) { if (t < o) rs[t] = fmaxf(rs[t], rs[t + o]); __syncthreads(); }
    const float m = rs[0]; __syncthreads();
    const float e = __expf(v - m);
    rs[t] = e; __syncthreads();
    for (int o = 128; o; o >>= 1) { if (t < o) rs[t] += rs[t + o]; __syncthreads(); }
    a[(long)n * 256 + t] = e / rs[0];
}

// ---------------- concat two [N,C] -> [N,2C] ----------------
__global__ __launch_bounds__(256) void concat_k(const float* __restrict__ a,
                                                const float* __restrict__ b,
                                                float* __restrict__ o)
{
    const long i = (long)blockIdx.x * 256 + threadIdx.x;
    const long n = i >> 9;
    const int c = (int)(i & 511);
    o[n * 1024 + c]       = a[i];
    o[n * 1024 + 512 + c] = b[i];
}

// ---------------- mean over T (partial + reduce) ----------------
__global__ __launch_bounds__(64) void meanp_k(const float* __restrict__ A, int lda,
                                              float* __restrict__ part)
{
    const int bid = blockIdx.x;
    const int ts = bid & 15;
    const int cg = (bid >> 4) & 7;
    const int b  = bid >> 7;
    const int c  = cg * 64 + threadIdx.x;
    const float* p = A + ((long)b * TLEN + ts * 64) * lda + c;
    float s = 0.f;
    for (int t = 0; t < 64; ++t) s += p[(long)t * lda];
    part[(long)ts * 1024 + b * 512 + c] = s;
}
__global__ __launch_bounds__(256) void meanr_k(const float* __restrict__ part,
                                               float* __restrict__ hm)
{
    const int i = blockIdx.x * 256 + threadIdx.x;
    float s = 0.f;
    for (int ts = 0; ts < 16; ++ts) s += part[ts * 1024 + i];
    hm[i] = s * (1.f / 1024.f);
}

// ---------------- awareness ----------------
__global__ __launch_bounds__(64) void aware_k(const float* __restrict__ hm,
                                              const float* __restrict__ aw_w,
                                              const float* __restrict__ aw_b,
                                              int lp, float* __restrict__ out)
{
    const int t = threadIdx.x;
    if (t < NB * NH) {
        const int b = t >> 3, hh = t & 7;
        const float* W = aw_w + (long)lp * CDIM * NH;
        const float* x = hm + b * CDIM;
        float s = aw_b[lp * NH + hh];
        for (int c = 0; c < CDIM; ++c) s += x[c] * W[c * NH + hh];
        out[t] = s;
    }
}

// ---------------- fused attention (8 rows per block) ----------------
__global__ __launch_bounds__(256) void attn_k(
    const float* __restrict__ qkv,
    const float* __restrict__ dscale, int lp,
    const float* __restrict__ aware,
    float* __restrict__ prior,
    int use_prior,
    float* __restrict__ outs, int ldouts, int out_off)
{
    const int tid = threadIdx.x;
    const int rblk = blockIdx.x % (TLEN / 8);
    const int bh = blockIdx.x / (TLEN / 8);
    const int b = bh / NH, h = bh % NH;
    const int t0 = rblk * 8;
    __shared__ float qs[8][64];
    __shared__ float kt[64][68];
    __shared__ float ss[8][1024];
    __shared__ float rinv[8];
    const float scale = dscale[lp] * aware[bh];
    for (int i = tid; i < 512; i += 256) {
        const int r = i >> 6, d = i & 63;
        qs[r][d] = qkv[(long)(b * TLEN + t0 + r) * 1536 + h * 64 + d] * scale;
    }
    __syncthreads();
    for (int s0 = 0; s0 < TLEN; s0 += 64) {
        for (int i = tid; i < 4096; i += 256) {
            const int sr = i >> 6, d = i & 63;
            kt[sr][d] = qkv[(long)(b * TLEN + s0 + sr) * 1536 + 512 + h * 64 + d];
        }
        __syncthreads();
        for (int i = tid; i < 512; i += 256) {
            const int r = i >> 6, c = i & 63;
            float acc = 0.f;
#pragma unroll
            for (int d = 0; d < 64; d += 4) {
                const float4 qv = *(const float4*)&qs[r][d];
                const float4 kv = *(const float4*)&kt[c][d];
                acc += qv.x * kv.x + qv.y * kv.y + qv.z * kv.z + qv.w * kv.w;
            }
            ss[r][s0 + c] = acc;
        }
        __syncthreads();
    }
    {
        const int r = tid >> 5, lane = tid & 31;
        float m = -1e30f;
        for (int c = lane; c < TLEN; c += 32) m = fmaxf(m, ss[r][c]);
        for (int o = 16; o; o >>= 1) m = fmaxf(m, __shfl_down(m, o, 32));
        m = __shfl(m, 0, 32);
        float sum = 0.f;
        for (int c = lane; c < TLEN; c += 32) {
            const float e = __expf(ss[r][c] - m);
            ss[r][c] = e;
            sum += e;
        }
        for (int o = 16; o; o >>= 1) sum += __shfl_down(sum, o, 32);
        if (lane == 0) rinv[r] = 1.f / sum;
    }
    __syncthreads();
    {
        const long pbase = ((long)bh * TLEN + t0) * TLEN;
        for (int i = tid; i < 8 * TLEN; i += 256) {
            const int r = i >> 10, c = i & 1023;
            float v = ss[r][c] * rinv[r];
            if (use_prior) v += 0.3f * prior[pbase + (long)r * TLEN + c];
            ss[r][c] = v;
            prior[pbase + (long)r * TLEN + c] = v;
        }
    }
    __syncthreads();
    float oacc0 = 0.f, oacc1 = 0.f;
    for (int s0 = 0; s0 < TLEN; s0 += 64) {
        for (int i = tid; i < 4096; i += 256) {
            const int sr = i >> 6, d = i & 63;
            kt[sr][d] = qkv[(long)(b * TLEN + s0 + sr) * 1536 + 1024 + h * 64 + d];
        }
        __syncthreads();
        {
            const int r0 = tid >> 6, d0 = tid & 63;
            const int r1 = (tid + 256) >> 6, d1 = (tid + 256) & 63;
            float a0 = 0.f, a1 = 0.f;
#pragma unroll
            for (int sr = 0; sr < 64; ++sr) {
                a0 += ss[r0][s0 + sr] * kt[sr][d0];
                a1 += ss[r1][s0 + sr] * kt[sr][d1];
            }
            oacc0 += a0; oacc1 += a1;
        }
        __syncthreads();
    }
    {
        const int r0 = tid >> 6, d0 = tid & 63;
        const int r1 = (tid + 256) >> 6, d1 = (tid + 256) & 63;
        float v0 = oacc0 / (1.f + __expf(-oacc0));
        float v1 = oacc1 / (1.f + __expf(-oacc1));
        outs[(long)(b * TLEN + t0 + r0) * ldouts + out_off + h * 64 + d0] = v0;
        outs[(long)(b * TLEN + t0 + r1) * ldouts + out_off + h * 64 + d1] = v1;
    }
}

// ---------------- layernorm over C=512 ----------------
__global__ __launch_bounds__(256) void ln_k(const float* __restrict__ z,
                                            const float* __restrict__ g,
                                            const float* __restrict__ bb,
                                            float* __restrict__ xn)
{
    const int n = blockIdx.x, t = threadIdx.x;
    __shared__ float rs[256], rq[256];
    const float v0 = z[(long)n * 512 + t];
    const float v1 = z[(long)n * 512 + 256 + t];
    rs[t] = v0 + v1;
    rq[t] = v0 * v0 + v1 * v1;
    __syncthreads();
    for (int o = 128; o; o >>= 1) {
        if (t < o) { rs[t] += rs[t + o]; rq[t] += rq[t + o]; }
        __syncthreads();
    }
    const float mu = rs[0] * (1.f / 512.f);
    const float var = rq[0] * (1.f / 512.f) - mu * mu;
    const float rstd = rsqrtf(var + 1e-5f);
    xn[(long)n * 512 + t]       = (v0 - mu) * rstd * g[t] + bb[t];
    xn[(long)n * 512 + 256 + t] = (v1 - mu) * rstd * g[t + 256] + bb[t + 256];
}

// ---------------- MoE gate ----------------
__global__ __launch_bounds__(64) void gate_k(const float* __restrict__ xn,
                                             const float* __restrict__ gw,
                                             const float* __restrict__ gb,
                                             int l, float* __restrict__ wv,
                                             int* __restrict__ eidx)
{
    const int n = blockIdx.x, t = threadIdx.x;
    const int e = t & 7, ch = t >> 3;
    const float* W = gw + (long)l * CDIM * 8;
    float part = 0.f;
    for (int k = ch * 64; k < ch * 64 + 64; ++k) part += xn[(long)n * CDIM + k] * W[k * 8 + e];
    part += __shfl_xor(part, 8, 64);
    part += __shfl_xor(part, 16, 64);
    part += __shfl_xor(part, 32, 64);
    __shared__ float lg[8];
    if (t < 8) lg[t] = part + gb[l * 8 + t];
    __syncthreads();
    if (t == 0) {
        float m = lg[0];
        for (int i = 1; i < 8; ++i) m = fmaxf(m, lg[i]);
        float p[8], s = 0.f;
        for (int i = 0; i < 8; ++i) { p[i] = __expf(lg[i] - m); s += p[i]; }
        const float inv = 1.f / s;
        int i0 = 0;
        for (int i = 1; i < 8; ++i) if (p[i] > p[i0]) i0 = i;
        int i1 = (i0 == 0) ? 1 : 0;
        for (int i = 0; i < 8; ++i) { if (i == i0) continue; if (p[i] > p[i1]) i1 = i; }
        eidx[n * 2] = i0; eidx[n * 2 + 1] = i1;
        wv[n * 2] = p[i0] * inv; wv[n * 2 + 1] = p[i1] * inv;
    }
}

// ---------------- quality ----------------
__global__ __launch_bounds__(256) void qual_k(const float* __restrict__ t1,
                                              const float* __restrict__ q2w,
                                              const float* __restrict__ q2b,
                                              int l, float* __restrict__ qual)
{
    const int n = blockIdx.x, t = threadIdx.x;
    const float* W = q2w + (long)l * 2048;
    float s = 0.f;
    for (int k = t; k < 2048; k += 256) s += t1[(long)n * 2048 + k] * W[k];
    __shared__ float rs[256];
    rs[t] = s; __syncthreads();
    for (int o = 128; o; o >>= 1) { if (t < o) rs[t] += rs[t + o]; __syncthreads(); }
    if (t == 0) {
        const float q = rs[0] + q2b[l];
        qual[n] = 1.f / (1.f + __expf(-q));
    }
}

// ---------------- xq = x_in * (1 - quality) ----------------
__global__ __launch_bounds__(256) void xq_k(const float* __restrict__ x_in,
                                            const float* __restrict__ qual,
                                            float* __restrict__ xq)
{
    const long i = (long)blockIdx.x * 256 + threadIdx.x;
    const long n = i >> 9;
    xq[i] = x_in[i] * (1.f - qual[n]);
}

// ---------------- x = reason + gate*pscale*intro ----------------
__global__ __launch_bounds__(256) void final_k(const float* __restrict__ reason,
                                               const float* __restrict__ gate,
                                               const float* __restrict__ pscale,
                                               const float* __restrict__ intro,
                                               float* __restrict__ xo)
{
    const long i = (long)blockIdx.x * 256 + threadIdx.x;
    const int c = (int)(i & 511);
    xo[i] = reason[i] + gate[i] * pscale[c] * intro[i];
}

// =======================================================================
extern "C" void kernel_launch(void* const* d_in, const int* in_sizes, int n_in,
                              void* d_out, int out_size, void* d_ws, size_t ws_size,
                              hipStream_t stream)
{
    (void)in_sizes; (void)n_in; (void)out_size; (void)ws_size;
    const int*   ids     = (const int*)  d_in[0];
    const float* embed_w = (const float*)d_in[1];
    const float* mem     = (const float*)d_in[2];
    const float* mp_w    = (const float*)d_in[3];
    const float* mp_b    = (const float*)d_in[4];
    const float* qkv_w   = (const float*)d_in[5];
    const float* qkv_b   = (const float*)d_in[6];
    const float* aw_w    = (const float*)d_in[7];
    const float* aw_b    = (const float*)d_in[8];
    const float* dscale  = (const float*)d_in[9];
    const float* mg_w    = (const float*)d_in[10];
    const float* mg_b    = (const float*)d_in[11];
    const float* ln_g    = (const float*)d_in[12];
    const float* ln_b    = (const float*)d_in[13];
    const float* gw      = (const float*)d_in[14];
    const float* gb      = (const float*)d_in[15];
    const float* ew1     = (const float*)d_in[16];
    const float* eb1     = (const float*)d_in[17];
    const float* ew2     = (const float*)d_in[18];
    const float* eb2     = (const float*)d_in[19];
    const float* q1w     = (const float*)d_in[20];
    const float* q1b     = (const float*)d_in[21];
    const float* q2w     = (const float*)d_in[22];
    const float* q2b     = (const float*)d_in[23];
    const float* errw    = (const float*)d_in[24];
    const float* errb    = (const float*)d_in[25];
    const float* ag1w    = (const float*)d_in[26];
    const float* ag1b    = (const float*)d_in[27];
    const float* ag2w    = (const float*)d_in[28];
    const float* ag2b    = (const float*)d_in[29];
    const float* pscale  = (const float*)d_in[30];
    const float* head_w  = (const float*)d_in[31];
    const float* head_b  = (const float*)d_in[32];
    float* out = (float*)d_out;
    float* ws  = (float*)d_ws;

    const long NC = (long)NTOK * CDIM; // 1,048,576
    float* X0   = ws;
    float* X1   = ws + NC;
    float* RET  = ws + 2 * NC;
    float* XCAT = ws + 3 * NC;       // [N,2C]
    float* QKV  = ws + 5 * NC;       // [N,3C]
    float* OUTS = ws + 8 * NC;       // [N,2C]
    float* EN   = ws + 10 * NC;      // [N,256]
    float* SM   = ws + 10 * NC + NC / 2;
    float* PART = SM;
    float* HMEAN= SM + 16384;
    float* AWARE= SM + 17408;
    float* QUAL = SM + 17472;
    float* WV   = SM + 19520;
    int*   EIDX = (int*)(SM + 23616);
    int*   OFFI = (int*)(SM + 27712);   // 16 ints
    int*   LIST = (int*)(SM + 27728);   // 5120 ints
    int*   POSMAP = (int*)(SM + 32848); // 4096 ints (ends < SM + NC/2)
    float* R      = ws + 11 * NC;    // overlay: prior [B,H,T,T] = 16*NC
    float* PRIOR  = R;
    float* Z      = R;
    float* XN     = R + NC;
    float* REASON = R + 2 * NC;
    float* INTRO  = R + 3 * NC;
    float* XQ     = R + 4 * NC;
    float* GATEB  = R + 5 * NC;
    __bf16* EHB   = (__bf16*)(R + 6 * NC); // [5120,1024] bf16 = 2.5*NC floats
    float* EYS    = R + 9 * NC;            // [5120,512] f32 = 2.5*NC floats
    float* Q1B    = R + 12 * NC;     // [N,2048]

    // bf16 region after 27*NC floats
    __bf16* bfw = (__bf16*)(ws + 27 * NC);
    __bf16* WB_mp   = bfw;                       // 512*1024
    __bf16* WB_qkv  = bfw + 524288;              // 4 * 1536*512
    __bf16* WB_mg   = bfw + 3670016;             // 2 * 512*1024
    __bf16* WB_q1   = bfw + 4718592;             // 2 * 2048*512
    __bf16* WB_err  = bfw + 6815744;             // 2 * 512*512
    __bf16* WB_ag1  = bfw + 7340032;             // 2048*1024
    __bf16* WB_ag2  = bfw + 9437184;             // 512*2048
    __bf16* WB_memn = bfw + 10485760;            // 256*512
    __bf16* WB_memt = bfw + 10616832;            // 512*256
    __bf16* WB_head = bfw + 10747904;            // 32000*512
    __bf16* ABF     = bfw + 27131904;            // up to 2048*2048
    __bf16* WB_e1   = bfw + 31326208;            // 16 * 1024*512 (ew1^T per l,e)
    __bf16* WB_e2   = bfw + 39714816;            // 16 * 512*1024 (ew2^T per l,e)

    auto wtrans = [&](const float* W, __bf16* Wt, int K, int N) {
        wtrans_k<<<dim3(N / 64, K / 64), 256, 0, stream>>>(W, Wt, K, N);
    };
    auto gemm = [&](const float* Asrc, int lda, const __bf16* B, float* C_, int ldc,
                    const float* bias, const float* res, int ldres, float alpha,
                    int Nn, int K, int act) {
        cvta_k<<<NTOK, 256, 0, stream>>>(Asrc, lda, K, ABF);
        gemm_bf16<<<dim3(Nn / 128, NTOK / 128), 256, 0, stream>>>(
            ABF, B, C_, ldc, bias, res, ldres, alpha, K, act);
    };

    // ---- weight conversion (same work every call; graph-safe) ----
    wtrans(mp_w, WB_mp, 1024, 512);
    for (int lp = 0; lp < 4; ++lp)
        wtrans(qkv_w + (long)lp * 512 * 1536, WB_qkv + (long)lp * 1536 * 512, 512, 1536);
    for (int l = 0; l < 2; ++l) {
        wtrans(mg_w + (long)l * 1024 * 512, WB_mg + (long)l * 512 * 1024, 1024, 512);
        wtrans(q1w + (long)l * 512 * 2048, WB_q1 + (long)l * 2048 * 512, 512, 2048);
        wtrans(errw + (long)l * 512 * 512, WB_err + (long)l * 512 * 512, 512, 512);
    }
    for (int le = 0; le < 16; ++le) {
        wtrans(ew1 + (long)le * 524288, WB_e1 + (long)le * 524288, 512, 1024);
        wtrans(ew2 + (long)le * 524288, WB_e2 + (long)le * 524288, 1024, 512);
    }
    wtrans(ag1w, WB_ag1, 1024, 2048);
    wtrans(ag2w, WB_ag2, 2048, 512);
    wtrans(head_w, WB_head, 512, VDIM);
    wtrans(mem, WB_memt, 256, 512);                     // mem^T [512,256]
    cvta_k<<<256, 256, 0, stream>>>(mem, 512, 512, WB_memn); // mem [256,512] as [N,K]

    // ---- embedding + memory bank ----
    embed_k<<<NTOK, 256, 0, stream>>>(ids, embed_w, X0);
    gemm(X0, 512, WB_memn, EN, 256, nullptr, nullptr, 0, 1.f, 256, 512, 0);
    smrows_k<<<NTOK, 256, 0, stream>>>(EN);
    gemm(EN, 256, WB_memt, RET, 512, nullptr, nullptr, 0, 1.f, 512, 256, 0);
    concat_k<<<4096, 256, 0, stream>>>(X0, RET, XCAT);
    gemm(XCAT, 1024, WB_mp, X0, 512, mp_b, nullptr, 0, 1.f, 512, 1024, 0);

    float* xcur = X0;
    float* xalt = X1;
    for (int l = 0; l < 2; ++l) {
        for (int p = 0; p < 2; ++p) {
            const int lp = l * 2 + p;
            const float* hptr = (p == 0) ? xcur : OUTS;
            const int hlda = (p == 0) ? 512 : 1024;
            gemm(hptr, hlda, WB_qkv + (long)lp * 1536 * 512, QKV, 1536,
                 qkv_b + (long)lp * 1536, nullptr, 0, 1.f, 1536, 512, 0);
            meanp_k<<<256, 64, 0, stream>>>(hptr, hlda, PART);
            meanr_k<<<4, 256, 0, stream>>>(PART, HMEAN);
            aware_k<<<1, 64, 0, stream>>>(HMEAN, aw_w, aw_b, lp, AWARE);
            attn_k<<<NB * NH * (TLEN / 8), 256, 0, stream>>>(
                QKV, dscale, lp, AWARE, PRIOR, (p == 1) ? 1 : 0, OUTS, 1024, p * CDIM);
        }
        gemm(OUTS, 1024, WB_mg + (long)l * 512 * 1024, Z, 512, mg_b + (long)l * 512,
             xcur, 512, 1.f, 512, 1024, 0);
        ln_k<<<NTOK, 256, 0, stream>>>(Z, ln_g + (long)l * 512, ln_b + (long)l * 512, XN);
        gate_k<<<NTOK, 64, 0, stream>>>(XN, gw, gb, l, WV, EIDX);
        route_k<<<1, 256, 0, stream>>>(EIDX, OFFI, LIST, POSMAP);
        cvta_k<<<NTOK, 256, 0, stream>>>(XN, 512, 512, ABF);
        moe_g1_k<<<dim3(8, 40), 256, 0, stream>>>(ABF, WB_e1 + (long)l * 8 * 524288,
                eb1 + (long)l * 8192, OFFI, LIST, EHB);
        moe_g2_k<<<dim3(4, 40), 256, 0, stream>>>(EHB, WB_e2 + (long)l * 8 * 524288,
                eb2 + (long)l * 4096, OFFI, EYS);
        reason2_k<<<4096, 256, 0, stream>>>(XN, EYS, WV, POSMAP, REASON);
        gemm(xcur, 512, WB_q1 + (long)l * 2048 * 512, Q1B, 2048, q1b + (long)l * 2048,
             nullptr, 0, 1.f, 2048, 512, 1);
        qual_k<<<NTOK, 256, 0, stream>>>(Q1B, q2w, q2b, l, QUAL);
        xq_k<<<4096, 256, 0, stream>>>(xcur, QUAL, XQ);
        gemm(XQ, 512, WB_err + (long)l * 512 * 512, INTRO, 512, errb + (long)l * 512,
             xcur, 512, 0.3f, 512, 512, 0);
        concat_k<<<4096, 256, 0, stream>>>(REASON, INTRO, XCAT);
        gemm(XCAT, 1024, WB_ag1, Q1B, 2048, ag1b, nullptr, 0, 1.f, 2048, 1024, 1);
        gemm(Q1B, 2048, WB_ag2, GATEB, 512, ag2b, nullptr, 0, 1.f, 512, 2048, 2);
        final_k<<<4096, 256, 0, stream>>>(REASON, GATEB, pscale, INTRO, xalt);
        float* tmp = xcur; xcur = xalt; xalt = tmp;
    }
    // ---- head ----
    gemm(xcur, 512, WB_head, out, VDIM, head_b, nullptr, 0, 1.f, VDIM, 512, 0);
}

// Round 2
// 1695.223 us; speedup vs baseline: 2.7976x; 1.5933x over previous
//
#include <hip/hip_runtime.h>

// ConsciousTransformer forward. Round 4: attention moved from scalar-fp32 VALU
// (316us/dispatch, MfmaUtil=0) to bf16 MFMA with LDS-resident S-tile,
// XOR-swizzled LDS, double-buffered global_load_lds staging, bf16 prior.
// Dims: C=512, V=32000, L=2, P=2, E=8, HM=1024, H=8, M=256, B=2, T=1024, N=B*T=2048

#define NTOK 2048
#define CDIM 512
#define TLEN 1024
#define NB 2
#define NH 8
#define VDIM 32000

typedef __attribute__((ext_vector_type(4))) float f32x4;
typedef __attribute__((ext_vector_type(8))) __bf16 bf16x8;

#define AS1 __attribute__((address_space(1)))
#define AS3 __attribute__((address_space(3)))

__device__ __forceinline__ void g2lds16(const void* g, void* l) {
    __builtin_amdgcn_global_load_lds((const AS1 void*)g, (AS3 void*)l, 16, 0, 0);
}

// ---------------- bf16 MFMA GEMM: C = res + alpha*act(A@B^T + bias) ----------------
// A [M,K] bf16 packed, B [N,K] bf16 packed, C [M,N] fp32 (ldc).
// act: 0=none, 1=silu, 2=tanh. M,N mult of 128; K mult of 32.
__global__ __launch_bounds__(256) void gemm_bf16(
    const __bf16* __restrict__ A,
    const __bf16* __restrict__ B,
    float* __restrict__ C_, int ldc,
    const float* __restrict__ bias,
    const float* __restrict__ res, int ldres, float alpha,
    int K, int act)
{
    __shared__ __bf16 As[128 * 32];
    __shared__ __bf16 Bs[128 * 32];
    const int tid = threadIdx.x;
    const int w = tid >> 6, lane = tid & 63;
    const int m0 = blockIdx.y * 128, n0 = blockIdx.x * 128;
    const int wr = (w >> 1) * 64, wc = (w & 1) * 64;
    f32x4 acc[4][4] = {};
    const int mrow = lane & 15, kq = (lane >> 4) * 8;
    for (int k0 = 0; k0 < K; k0 += 32) {
#pragma unroll
        for (int i = 0; i < 2; ++i) {
            const int boff = w * 2048 + i * 1024 + lane * 16; // byte off in 128x32 bf16 tile
            const int row = boff >> 6;        // 64 B per row
            const int ke = (boff & 63) >> 1;  // bf16 elem within row
            g2lds16(A + (long)(m0 + row) * K + k0 + ke, (char*)As + (boff - lane * 16));
            g2lds16(B + (long)(n0 + row) * K + k0 + ke, (char*)Bs + (boff - lane * 16));
        }
        __syncthreads();
        bf16x8 af[4], bfr[4];
#pragma unroll
        for (int i = 0; i < 4; ++i)
            af[i] = *(const bf16x8*)(As + (wr + i * 16 + mrow) * 32 + kq);
#pragma unroll
        for (int j = 0; j < 4; ++j)
            bfr[j] = *(const bf16x8*)(Bs + (wc + j * 16 + mrow) * 32 + kq);
#pragma unroll
        for (int i = 0; i < 4; ++i)
#pragma unroll
            for (int j = 0; j < 4; ++j)
                acc[i][j] = __builtin_amdgcn_mfma_f32_16x16x32_bf16(af[i], bfr[j], acc[i][j], 0, 0, 0);
        __syncthreads();
    }
    const int col_l = lane & 15, row_l = (lane >> 4) * 4;
#pragma unroll
    for (int i = 0; i < 4; ++i)
#pragma unroll
        for (int j = 0; j < 4; ++j) {
            const int n = n0 + wc + j * 16 + col_l;
            const float bv = bias ? bias[n] : 0.f;
#pragma unroll
            for (int r = 0; r < 4; ++r) {
                const int m = m0 + wr + i * 16 + row_l + r;
                float v = acc[i][j][r] + bv;
                if (act == 1) v = v / (1.f + __expf(-v));
                else if (act == 2) v = tanhf(v);
                v *= alpha;
                if (res) v += res[(long)m * ldres + n];
                C_[(long)m * ldc + n] = v;
            }
        }
}

// ---------------- MoE routing: per-expert 128-aligned segments ----------------
__global__ __launch_bounds__(256) void route_k(const int* __restrict__ eidx,
                                               int* __restrict__ offi,
                                               int* __restrict__ list,
                                               int* __restrict__ posmap)
{
    __shared__ int cnt[8], fill[8], seg[9];
    const int t = threadIdx.x;
    if (t < 8) cnt[t] = 0;
    __syncthreads();
    for (int i = t; i < NTOK * 2; i += 256) atomicAdd(&cnt[eidx[i]], 1);
    __syncthreads();
    if (t == 0) {
        int run = 0;
        for (int e = 0; e < 8; ++e) {
            seg[e] = run;
            run += (cnt[e] + 127) & ~127;
        }
        seg[8] = run;
    }
    __syncthreads();
    if (t < 8) fill[t] = seg[t];
    if (t < 9) offi[t] = seg[t];
    __syncthreads();
    for (int i = t; i < NTOK * 2; i += 256) {
        const int e = eidx[i];
        const int g = atomicAdd(&fill[e], 1);
        list[g] = i;
        posmap[i] = g;
    }
    __syncthreads();
#pragma unroll
    for (int e = 0; e < 8; ++e)
        for (int g = seg[e] + cnt[e] + t; g < seg[e + 1]; g += 256) list[g] = 0;
}

// ---------------- MoE mlp1: gathered-A GEMM + swiglu, bf16 out ----------------
__global__ __launch_bounds__(256) void moe_g1_k(
    const __bf16* __restrict__ A,
    const __bf16* __restrict__ Bw,
    const float* __restrict__ eb1l,
    const int* __restrict__ offi,
    const int* __restrict__ list,
    __bf16* __restrict__ EHB)
{
    const int m0 = blockIdx.y * 128;
    if (m0 >= offi[8]) return;
    int e = 0;
    while (e < 7 && offi[e + 1] <= m0) ++e;   // segments are 128-aligned
    const __bf16* B = Bw + (long)e * (1024 * 512);
    const float* bias = eb1l + e * 1024;
    __shared__ __bf16 As[128 * 32];
    __shared__ __bf16 Bs[128 * 32];
    __shared__ int toks[128];
    const int tid = threadIdx.x;
    if (tid < 128) toks[tid] = list[m0 + tid] >> 1;
    __syncthreads();
    const int w = tid >> 6, lane = tid & 63;
    const int n0 = blockIdx.x * 128;
    const int wr = (w >> 1) * 64, wc = (w & 1) * 64;
    f32x4 acc[4][4] = {};
    const int mrow = lane & 15, kq = (lane >> 4) * 8;
    for (int k0 = 0; k0 < 512; k0 += 32) {
#pragma unroll
        for (int i = 0; i < 2; ++i) {
            const int boff = w * 2048 + i * 1024 + lane * 16;
            const int row = boff >> 6;
            const int ke = (boff & 63) >> 1;
            g2lds16(A + (long)toks[row] * 512 + k0 + ke, (char*)As + (boff - lane * 16));
            g2lds16(B + (long)(n0 + row) * 512 + k0 + ke, (char*)Bs + (boff - lane * 16));
        }
        __syncthreads();
        bf16x8 af[4], bfr[4];
#pragma unroll
        for (int i = 0; i < 4; ++i)
            af[i] = *(const bf16x8*)(As + (wr + i * 16 + mrow) * 32 + kq);
#pragma unroll
        for (int j = 0; j < 4; ++j)
            bfr[j] = *(const bf16x8*)(Bs + (wc + j * 16 + mrow) * 32 + kq);
#pragma unroll
        for (int i = 0; i < 4; ++i)
#pragma unroll
            for (int j = 0; j < 4; ++j)
                acc[i][j] = __builtin_amdgcn_mfma_f32_16x16x32_bf16(af[i], bfr[j], acc[i][j], 0, 0, 0);
        __syncthreads();
    }
    const int col_l = lane & 15, row_l = (lane >> 4) * 4;
#pragma unroll
    for (int i = 0; i < 4; ++i)
#pragma unroll
        for (int j = 0; j < 4; ++j) {
            const int n = n0 + wc + j * 16 + col_l;
            const float bv = bias[n];
#pragma unroll
            for (int r = 0; r < 4; ++r) {
                const int g = m0 + wr + i * 16 + row_l + r;
                const float v = acc[i][j][r] + bv;
                EHB[(long)g * 1024 + n] = (__bf16)(v * v / (1.f + __expf(-v)));
            }
        }
}

// ---------------- MoE mlp2: segment-contiguous GEMM, f32 out ----------------
__global__ __launch_bounds__(256) void moe_g2_k(
    const __bf16* __restrict__ A,
    const __bf16* __restrict__ Bw,
    const float* __restrict__ eb2l,
    const int* __restrict__ offi,
    float* __restrict__ EYS)
{
    const int m0 = blockIdx.y * 128;
    if (m0 >= offi[8]) return;
    int e = 0;
    while (e < 7 && offi[e + 1] <= m0) ++e;
    const __bf16* B = Bw + (long)e * (512 * 1024);
    const float* bias = eb2l + e * 512;
    __shared__ __bf16 As[128 * 32];
    __shared__ __bf16 Bs[128 * 32];
    const int tid = threadIdx.x;
    const int w = tid >> 6, lane = tid & 63;
    const int n0 = blockIdx.x * 128;
    const int wr = (w >> 1) * 64, wc = (w & 1) * 64;
    f32x4 acc[4][4] = {};
    const int mrow = lane & 15, kq = (lane >> 4) * 8;
    for (int k0 = 0; k0 < 1024; k0 += 32) {
#pragma unroll
        for (int i = 0; i < 2; ++i) {
            const int boff = w * 2048 + i * 1024 + lane * 16;
            const int row = boff >> 6;
            const int ke = (boff & 63) >> 1;
            g2lds16(A + (long)(m0 + row) * 1024 + k0 + ke, (char*)As + (boff - lane * 16));
            g2lds16(B + (long)(n0 + row) * 1024 + k0 + ke, (char*)Bs + (boff - lane * 16));
        }
        __syncthreads();
        bf16x8 af[4], bfr[4];
#pragma unroll
        for (int i = 0; i < 4; ++i)
            af[i] = *(const bf16x8*)(As + (wr + i * 16 + mrow) * 32 + kq);
#pragma unroll
        for (int j = 0; j < 4; ++j)
            bfr[j] = *(const bf16x8*)(Bs + (wc + j * 16 + mrow) * 32 + kq);
#pragma unroll
        for (int i = 0; i < 4; ++i)
#pragma unroll
            for (int j = 0; j < 4; ++j)
                acc[i][j] = __builtin_amdgcn_mfma_f32_16x16x32_bf16(af[i], bfr[j], acc[i][j], 0, 0, 0);
        __syncthreads();
    }
    const int col_l = lane & 15, row_l = (lane >> 4) * 4;
#pragma unroll
    for (int i = 0; i < 4; ++i)
#pragma unroll
        for (int j = 0; j < 4; ++j) {
            const int n = n0 + wc + j * 16 + col_l;
            const float bv = bias[n];
#pragma unroll
            for (int r = 0; r < 4; ++r) {
                const int g = m0 + wr + i * 16 + row_l + r;
                EYS[(long)g * 512 + n] = acc[i][j][r] + bv;
            }
        }
}

// ---------------- reason = xn + 0.5*(w0*ey[pos0] + w1*ey[pos1]) ----------------
__global__ __launch_bounds__(256) void reason2_k(const float* __restrict__ xn,
                                                 const float* __restrict__ EYS,
                                                 const float* __restrict__ wv,
                                                 const int* __restrict__ posmap,
                                                 float* __restrict__ reason)
{
    const long i = (long)blockIdx.x * 256 + threadIdx.x;
    const long n = i >> 9;
    const int c = (int)(i & 511);
    const int g0 = posmap[n * 2], g1 = posmap[n * 2 + 1];
    const float v = wv[n * 2] * EYS[(long)g0 * 512 + c] + wv[n * 2 + 1] * EYS[(long)g1 * 512 + c];
    reason[i] = xn[i] + 0.5f * v;
}

// ---------------- weight transpose+convert (batched): W [K,N] f32 -> Wt [N,K] bf16 ----------------
__global__ __launch_bounds__(256) void wtrans_k(const float* __restrict__ W0,
                                                __bf16* __restrict__ Wt0, int K, int N,
                                                long sW, long sD)
{
    const float* W = W0 + (long)blockIdx.z * sW;
    __bf16* Wt = Wt0 + (long)blockIdx.z * sD;
    __shared__ float tile[64][65];
    const int k0 = blockIdx.y * 64, n0 = blockIdx.x * 64;
    const int t = threadIdx.x;
#pragma unroll
    for (int i = 0; i < 4; ++i) {
        const int r = (t >> 4) + i * 16;
        const int c = (t & 15) * 4;
        float4 v = *(const float4*)(W + (long)(k0 + r) * N + n0 + c);
        tile[r][c] = v.x; tile[r][c + 1] = v.y; tile[r][c + 2] = v.z; tile[r][c + 3] = v.w;
    }
    __syncthreads();
#pragma unroll
    for (int i = 0; i < 4; ++i) {
        const int rr = (t >> 4) + i * 16;   // n
        const int cc = (t & 15) * 4;        // k
        __bf16* o = Wt + (long)(n0 + rr) * K + k0 + cc;
        o[0] = (__bf16)tile[cc][rr];
        o[1] = (__bf16)tile[cc + 1][rr];
        o[2] = (__bf16)tile[cc + 2][rr];
        o[3] = (__bf16)tile[cc + 3][rr];
    }
}

// ---------------- activation convert: src [M,lda] f32 (first K cols) -> dst [M,K] bf16 ----------------
__global__ __launch_bounds__(256) void cvta_k(const float* __restrict__ src, int lda, int K,
                                              __bf16* __restrict__ dst)
{
    const int row = blockIdx.x, t = threadIdx.x;
    const float* s = src + (long)row * lda;
    __bf16* d = dst + (long)row * K;
    for (int c = t * 4; c < K; c += 1024) {
        float4 v = *(const float4*)(s + c);
        d[c] = (__bf16)v.x; d[c + 1] = (__bf16)v.y; d[c + 2] = (__bf16)v.z; d[c + 3] = (__bf16)v.w;
    }
}

// ---------------- embedding gather ----------------
__global__ __launch_bounds__(256) void embed_k(const int* __restrict__ ids,
                                               const float* __restrict__ ew,
                                               float* __restrict__ x)
{
    const int n = blockIdx.x, t = threadIdx.x;
    const long r = (long)ids[n] * CDIM;
    x[(long)n * CDIM + t]       = ew[r + t];
    x[(long)n * CDIM + 256 + t] = ew[r + 256 + t];
}

// ---------------- row softmax (width 256), in place ----------------
__global__ __launch_bounds__(256) void smrows_k(float* __restrict__ a)
{
    const int n = blockIdx.x, t = threadIdx.x;
    __shared__ float rs[256];
    float v = a[(long)n * 256 + t];
    rs[t] = v; __syncthreads();
    for (int o = 128; o; o >>= 1) { if (t < o) rs[t] = fmaxf(rs[t], rs[t + o]); __syncthreads(); }
    const float m = rs[0]; __syncthreads();
    const float e = __expf(v - m);
    rs[t] = e; __syncthreads();
    for (int o = 128; o; o >>= 1) { if (t < o) rs[t] += rs[t + o]; __syncthreads(); }
    a[(long)n * 256 + t] = e / rs[0];
}

// ---------------- concat two [N,C] -> [N,2C] ----------------
__global__ __launch_bounds__(256) void concat_k(const float* __restrict__ a,
                                                const float* __restrict__ b,
                                                float* __restrict__ o)
{
    const long i = (long)blockIdx.x * 256 + threadIdx.x;
    const long n = i >> 9;
    const int c = (int)(i & 511);
    o[n * 1024 + c]       = a[i];
    o[n * 1024 + 512 + c] = b[i];
}

// ---------------- mean over T (partial + reduce) ----------------
__global__ __launch_bounds__(64) void meanp_k(const float* __restrict__ A, int lda,
                                              float* __restrict__ part)
{
    const int bid = blockIdx.x;
    const int ts = bid & 15;
    const int cg = (bid >> 4) & 7;
    const int b  = bid >> 7;
    const int c  = cg * 64 + threadIdx.x;
    const float* p = A + ((long)b * TLEN + ts * 64) * lda + c;
    float s = 0.f;
    for (int t = 0; t < 64; ++t) s += p[(long)t * lda];
    part[(long)ts * 1024 + b * 512 + c] = s;
}
__global__ __launch_bounds__(256) void meanr_k(const float* __restrict__ part,
                                               float* __restrict__ hm)
{
    const int i = blockIdx.x * 256 + threadIdx.x;
    float s = 0.f;
    for (int ts = 0; ts < 16; ++ts) s += part[ts * 1024 + i];
    hm[i] = s * (1.f / 1024.f);
}

// ---------------- awareness ----------------
__global__ __launch_bounds__(64) void aware_k(const float* __restrict__ hm,
                                              const float* __restrict__ aw_w,
                                              const float* __restrict__ aw_b,
                                              int lp, float* __restrict__ out)
{
    const int t = threadIdx.x;
    if (t < NB * NH) {
        const int b = t >> 3, hh = t & 7;
        const float* W = aw_w + (long)lp * CDIM * NH;
        const float* x = hm + b * CDIM;
        float s = aw_b[lp * NH + hh];
        for (int c = 0; c < CDIM; ++c) s += x[c] * W[c * NH + hh];
        out[t] = s;
    }
}

// ---------------- per-phase attention prep: fp32 QKV -> bf16 Q*scale, K, V^T ----------------
// QKB/KB: [16 bh][1024][64] bf16; VTB: [16 bh][64][1024] bf16.
__global__ __launch_bounds__(256) void qkvprep_k(
    const float* __restrict__ qkv,
    const float* __restrict__ dscale, int lp,
    const float* __restrict__ aware,
    __bf16* __restrict__ QKB, __bf16* __restrict__ KB, __bf16* __restrict__ VTB)
{
    const int bh = blockIdx.x >> 4;
    const int tc = blockIdx.x & 15;
    const int b = bh >> 3, h = bh & 7;
    const int tid = threadIdx.x;
    const float sc = dscale[lp] * aware[bh];
    __shared__ float vt[64][68];
    const int row = tid >> 2, c0 = (tid & 3) * 16;
    const long rbase = ((long)(b * 1024 + tc * 64 + row)) * 1536 + h * 64 + c0;
    // Q (scaled) and K
    {
        bf16x8 qo[2], ko[2];
#pragma unroll
        for (int i = 0; i < 2; ++i)
#pragma unroll
            for (int jj = 0; jj < 2; ++jj) {
                const float4 qq = *(const float4*)(qkv + rbase + (i * 2 + jj) * 4);
                const float4 kk = *(const float4*)(qkv + rbase + 512 + (i * 2 + jj) * 4);
                qo[i][jj * 4 + 0] = (__bf16)(qq.x * sc);
                qo[i][jj * 4 + 1] = (__bf16)(qq.y * sc);
                qo[i][jj * 4 + 2] = (__bf16)(qq.z * sc);
                qo[i][jj * 4 + 3] = (__bf16)(qq.w * sc);
                ko[i][jj * 4 + 0] = (__bf16)kk.x;
                ko[i][jj * 4 + 1] = (__bf16)kk.y;
                ko[i][jj * 4 + 2] = (__bf16)kk.z;
                ko[i][jj * 4 + 3] = (__bf16)kk.w;
            }
        const long obase = (long)bh * 65536 + (long)(tc * 64 + row) * 64 + c0;
        *(bf16x8*)(QKB + obase) = qo[0];
        *(bf16x8*)(QKB + obase + 8) = qo[1];
        *(bf16x8*)(KB + obase) = ko[0];
        *(bf16x8*)(KB + obase + 8) = ko[1];
    }
    // V -> LDS (fp32) -> transposed bf16
    {
        const long vbase = ((long)(b * 1024 + tc * 64 + row)) * 1536 + 1024 + h * 64 + c0;
#pragma unroll
        for (int i = 0; i < 4; ++i) {
            const float4 v = *(const float4*)(qkv + vbase + i * 4);
            vt[row][c0 + i * 4 + 0] = v.x;
            vt[row][c0 + i * 4 + 1] = v.y;
            vt[row][c0 + i * 4 + 2] = v.z;
            vt[row][c0 + i * 4 + 3] = v.w;
        }
    }
    __syncthreads();
    {
        const int d = row;                 // 0..63
        const int s0 = c0;                 // 0,16,32,48
        bf16x8 o0, o1;
#pragma unroll
        for (int j = 0; j < 8; ++j) o0[j] = (__bf16)vt[s0 + j][d];
#pragma unroll
        for (int j = 0; j < 8; ++j) o1[j] = (__bf16)vt[s0 + 8 + j][d];
        __bf16* dst = VTB + (long)bh * 65536 + (long)d * 1024 + tc * 64 + s0;
        *(bf16x8*)dst = o0;
        *(bf16x8*)(dst + 8) = o1;
    }
}

// ---------------- MFMA attention: 32 Q-rows per block, full-row softmax + prior ----------------
// grid 512 = bh(16) x rowblock(32). LDS: qs 4KB + kv 2x16KB + ss 64KB = 100KB.
#define RB 32
__global__ __launch_bounds__(256) void attn2_k(
    const __bf16* __restrict__ QKB,
    const __bf16* __restrict__ KB,
    const __bf16* __restrict__ VTB,
    __bf16* __restrict__ prior,
    int use_prior,
    float* __restrict__ outs, int out_off)
{
    __shared__ __align__(16) __bf16 qs[RB * 64];
    __shared__ __align__(16) __bf16 kv[2][128 * 64];
    __shared__ __align__(16) __bf16 ss[RB * 1024];
    const int tid = threadIdx.x;
    const int w = tid >> 6, lane = tid & 63;
    const int rb = blockIdx.x & 31;
    const int bh = blockIdx.x >> 5;
    const int b = bh >> 3, h = bh & 7;
    const int t0 = rb * RB;
    const long qkbase = (long)bh * 65536;
    const int mrow = lane & 15, kq = (lane >> 4) * 8;

    // stage Q [32x64] (contiguous 4KB in QKB), swizzled source -> linear LDS
    {
        const int row = tid >> 3, gl = tid & 7;
        const int gs = gl ^ (row & 7);
        g2lds16(QKB + qkbase + (long)(t0 + row) * 64 + gs * 8,
                (char*)qs + tid * 16 - lane * 16);
    }
    // ---- S = Q@K^T phase, chunks of 128 keys, double-buffered K staging ----
    {
        // stage K chunk 0
        for (int it = 0; it < 4; ++it) {
            const int idx = it * 256 + tid;
            const int row = idx >> 3, gl = idx & 7;
            const int gs = gl ^ (row & 7);
            g2lds16(KB + qkbase + (long)row * 64 + gs * 8,
                    (char*)kv[0] + idx * 16 - lane * 16);
        }
        __syncthreads();
        int buf = 0;
        const int ntb = w * 2;   // wave owns chunk n-tiles {2w, 2w+1}
        for (int c = 0; c < 8; ++c) {
            if (c < 7) {
                const int s0n = (c + 1) * 128;
                for (int it = 0; it < 4; ++it) {
                    const int idx = it * 256 + tid;
                    const int row = idx >> 3, gl = idx & 7;
                    const int gs = gl ^ (row & 7);
                    g2lds16(KB + qkbase + (long)(s0n + row) * 64 + gs * 8,
                            (char*)kv[buf ^ 1] + idx * 16 - lane * 16);
                }
            }
            f32x4 accs[2][2] = {};
#pragma unroll
            for (int k0 = 0; k0 < 64; k0 += 32) {
                bf16x8 aq[2], bk[2];
#pragma unroll
                for (int mt = 0; mt < 2; ++mt) {
                    const int r = mt * 16 + mrow;
                    const int col = k0 + kq;
                    aq[mt] = *(const bf16x8*)(qs + r * 64 + (((col >> 3) ^ (r & 7)) << 3));
                }
#pragma unroll
                for (int j = 0; j < 2; ++j) {
                    const int nl = (ntb + j) * 16 + mrow;
                    const int col = k0 + kq;
                    bk[j] = *(const bf16x8*)(kv[buf] + nl * 64 + (((col >> 3) ^ (nl & 7)) << 3));
                }
#pragma unroll
                for (int mt = 0; mt < 2; ++mt)
#pragma unroll
                    for (int j = 0; j < 2; ++j)
                        accs[mt][j] = __builtin_amdgcn_mfma_f32_16x16x32_bf16(aq[mt], bk[j], accs[mt][j], 0, 0, 0);
            }
            const int col_l = lane & 15, row_l = (lane >> 4) * 4;
#pragma unroll
            for (int mt = 0; mt < 2; ++mt)
#pragma unroll
                for (int j = 0; j < 2; ++j) {
                    const int ccol = c * 128 + (ntb + j) * 16 + col_l;
#pragma unroll
                    for (int r = 0; r < 4; ++r) {
                        const int rr = mt * 16 + row_l + r;
                        ss[rr * 1024 + (((ccol >> 3) ^ (rr & 7)) << 3) + (ccol & 7)] = (__bf16)accs[mt][j][r];
                    }
                }
            __syncthreads();
            buf ^= 1;
        }
    }
    // stage V^T chunk 0 early (overlaps softmax)
    for (int it = 0; it < 4; ++it) {
        const int idx = it * 256 + tid;
        const int d = idx >> 4, gl = idx & 15;
        const int gs = gl ^ (d & 7);
        g2lds16(VTB + (long)bh * 65536 + (long)d * 1024 + gs * 8,
                (char*)kv[0] + idx * 16 - lane * 16);
    }
    // ---- softmax over full rows (8 lanes per row) + prior mix, P stored bf16 ----
    {
        const int r = tid >> 3;
        const int li = tid & 7;
        const int rsw = r & 7;
        float mx = -1e30f;
        for (int j = 0; j < 16; ++j) {
            const int c = j * 64 + li * 8;
            bf16x8 v = *(const bf16x8*)(ss + r * 1024 + (((c >> 3) ^ rsw) << 3));
#pragma unroll
            for (int q = 0; q < 8; ++q) mx = fmaxf(mx, (float)v[q]);
        }
        mx = fmaxf(mx, __shfl_xor(mx, 1));
        mx = fmaxf(mx, __shfl_xor(mx, 2));
        mx = fmaxf(mx, __shfl_xor(mx, 4));
        float sum = 0.f;
        for (int j = 0; j < 16; ++j) {
            const int c = j * 64 + li * 8;
            __bf16* p = ss + r * 1024 + (((c >> 3) ^ rsw) << 3);
            bf16x8 v = *(const bf16x8*)p;
            bf16x8 e;
#pragma unroll
            for (int q = 0; q < 8; ++q) {
                const float ev = __expf((float)v[q] - mx);
                sum += ev;
                e[q] = (__bf16)ev;
            }
            *(bf16x8*)p = e;
        }
        sum += __shfl_xor(sum, 1);
        sum += __shfl_xor(sum, 2);
        sum += __shfl_xor(sum, 4);
        const float rinv = 1.f / sum;
        const long pbase = ((long)bh * 1024 + t0 + r) * 1024;
        for (int j = 0; j < 16; ++j) {
            const int c = j * 64 + li * 8;
            __bf16* p = ss + r * 1024 + (((c >> 3) ^ rsw) << 3);
            bf16x8 v = *(const bf16x8*)p;
            bf16x8 o;
            if (use_prior) {
                bf16x8 pr = *(const bf16x8*)(prior + pbase + c);
#pragma unroll
                for (int q = 0; q < 8; ++q)
                    o[q] = (__bf16)((float)v[q] * rinv + 0.3f * (float)pr[q]);
            } else {
#pragma unroll
                for (int q = 0; q < 8; ++q)
                    o[q] = (__bf16)((float)v[q] * rinv);
            }
            *(bf16x8*)p = o;
            *(bf16x8*)(prior + pbase + c) = o;
        }
    }
    __syncthreads();
    // ---- O = P@V phase, double-buffered V^T staging ----
    {
        f32x4 po[2] = {};
        int buf = 0;
        const int mt = w >> 1;
        const int ntb2 = (w & 1) * 2;
        for (int c = 0; c < 8; ++c) {
            if (c < 7) {
                const int s0n = (c + 1) * 128;
                for (int it = 0; it < 4; ++it) {
                    const int idx = it * 256 + tid;
                    const int d = idx >> 4, gl = idx & 15;
                    const int gs = gl ^ (d & 7);
                    g2lds16(VTB + (long)bh * 65536 + (long)d * 1024 + s0n + gs * 8,
                            (char*)kv[buf ^ 1] + idx * 16 - lane * 16);
                }
            }
#pragma unroll
            for (int ks = 0; ks < 4; ++ks) {
                const int r = mt * 16 + mrow;
                const int cola = c * 128 + ks * 32 + kq;
                bf16x8 pa = *(const bf16x8*)(ss + r * 1024 + (((cola >> 3) ^ (r & 7)) << 3));
                bf16x8 vb[2];
#pragma unroll
                for (int j = 0; j < 2; ++j) {
                    const int d = (ntb2 + j) * 16 + mrow;
                    const int colv = ks * 32 + kq;
                    vb[j] = *(const bf16x8*)(kv[buf] + d * 128 + (((colv >> 3) ^ (d & 7)) << 3));
                }
                po[0] = __builtin_amdgcn_mfma_f32_16x16x32_bf16(pa, vb[0], po[0], 0, 0, 0);
                po[1] = __builtin_amdgcn_mfma_f32_16x16x32_bf16(pa, vb[1], po[1], 0, 0, 0);
            }
            __syncthreads();
            buf ^= 1;
        }
        const int col_l = lane & 15, row_l = (lane >> 4) * 4;
#pragma unroll
        for (int j = 0; j < 2; ++j) {
            const int d = out_off + h * 64 + (ntb2 + j) * 16 + col_l;
#pragma unroll
            for (int r = 0; r < 4; ++r) {
                const int trow = t0 + mt * 16 + row_l + r;
                float v = po[j][r];
                v = v / (1.f + __expf(-v));
                outs[((long)(b * 1024 + trow)) * 1024 + d] = v;
            }
        }
    }
}

// ---------------- layernorm over C=512 ----------------
__global__ __launch_bounds__(256) void ln_k(const float* __restrict__ z,
                                            const float* __restrict__ g,
                                            const float* __restrict__ bb,
                                            float* __restrict__ xn)
{
    const int n = blockIdx.x, t = threadIdx.x;
    __shared__ float rs[256], rq[256];
    const float v0 = z[(long)n * 512 + t];
    const float v1 = z[(long)n * 512 + 256 + t];
    rs[t] = v0 + v1;
    rq[t] = v0 * v0 + v1 * v1;
    __syncthreads();
    for (int o = 128; o; o >>= 1) {
        if (t < o) { rs[t] += rs[t + o]; rq[t] += rq[t + o]; }
        __syncthreads();
    }
    const float mu = rs[0] * (1.f / 512.f);
    const float var = rq[0] * (1.f / 512.f) - mu * mu;
    const float rstd = rsqrtf(var + 1e-5f);
    xn[(long)n * 512 + t]       = (v0 - mu) * rstd * g[t] + bb[t];
    xn[(long)n * 512 + 256 + t] = (v1 - mu) * rstd * g[t + 256] + bb[t + 256];
}

// ---------------- MoE gate ----------------
__global__ __launch_bounds__(64) void gate_k(const float* __restrict__ xn,
                                             const float* __restrict__ gw,
                                             const float* __restrict__ gb,
                                             int l, float* __restrict__ wv,
                                             int* __restrict__ eidx)
{
    const int n = blockIdx.x, t = threadIdx.x;
    const int e = t & 7, ch = t >> 3;
    const float* W = gw + (long)l * CDIM * 8;
    float part = 0.f;
    for (int k = ch * 64; k < ch * 64 + 64; ++k) part += xn[(long)n * CDIM + k] * W[k * 8 + e];
    part += __shfl_xor(part, 8, 64);
    part += __shfl_xor(part, 16, 64);
    part += __shfl_xor(part, 32, 64);
    __shared__ float lg[8];
    if (t < 8) lg[t] = part + gb[l * 8 + t];
    __syncthreads();
    if (t == 0) {
        float m = lg[0];
        for (int i = 1; i < 8; ++i) m = fmaxf(m, lg[i]);
        float p[8], s = 0.f;
        for (int i = 0; i < 8; ++i) { p[i] = __expf(lg[i] - m); s += p[i]; }
        const float inv = 1.f / s;
        int i0 = 0;
        for (int i = 1; i < 8; ++i) if (p[i] > p[i0]) i0 = i;
        int i1 = (i0 == 0) ? 1 : 0;
        for (int i = 0; i < 8; ++i) { if (i == i0) continue; if (p[i] > p[i1]) i1 = i; }
        eidx[n * 2] = i0; eidx[n * 2 + 1] = i1;
        wv[n * 2] = p[i0] * inv; wv[n * 2 + 1] = p[i1] * inv;
    }
}

// ---------------- quality ----------------
__global__ __launch_bounds__(256) void qual_k(const float* __restrict__ t1,
                                              const float* __restrict__ q2w,
                                              const float* __restrict__ q2b,
                                              int l, float* __restrict__ qual)
{
    const int n = blockIdx.x, t = threadIdx.x;
    const float* W = q2w + (long)l * 2048;
    float s = 0.f;
    for (int k = t; k < 2048; k += 256) s += t1[(long)n * 2048 + k] * W[k];
    __shared__ float rs[256];
    rs[t] = s; __syncthreads();
    for (int o = 128; o; o >>= 1) { if (t < o) rs[t] += rs[t + o]; __syncthreads(); }
    if (t == 0) {
        const float q = rs[0] + q2b[l];
        qual[n] = 1.f / (1.f + __expf(-q));
    }
}

// ---------------- xq = x_in * (1 - quality) ----------------
__global__ __launch_bounds__(256) void xq_k(const float* __restrict__ x_in,
                                            const float* __restrict__ qual,
                                            float* __restrict__ xq)
{
    const long i = (long)blockIdx.x * 256 + threadIdx.x;
    const long n = i >> 9;
    xq[i] = x_in[i] * (1.f - qual[n]);
}

// ---------------- x = reason + gate*pscale*intro ----------------
__global__ __launch_bounds__(256) void final_k(const float* __restrict__ reason,
                                               const float* __restrict__ gate,
                                               const float* __restrict__ pscale,
                                               const float* __restrict__ intro,
                                               float* __restrict__ xo)
{
    const long i = (long)blockIdx.x * 256 + threadIdx.x;
    const int c = (int)(i & 511);
    xo[i] = reason[i] + gate[i] * pscale[c] * intro[i];
}

// =======================================================================
extern "C" void kernel_launch(void* const* d_in, const int* in_sizes, int n_in,
                              void* d_out, int out_size, void* d_ws, size_t ws_size,
                              hipStream_t stream)
{
    (void)in_sizes; (void)n_in; (void)out_size; (void)ws_size;
    const int*   ids     = (const int*)  d_in[0];
    const float* embed_w = (const float*)d_in[1];
    const float* mem     = (const float*)d_in[2];
    const float* mp_w    = (const float*)d_in[3];
    const float* mp_b    = (const float*)d_in[4];
    const float* qkv_w   = (const float*)d_in[5];
    const float* qkv_b   = (const float*)d_in[6];
    const float* aw_w    = (const float*)d_in[7];
    const float* aw_b    = (const float*)d_in[8];
    const float* dscale  = (const float*)d_in[9];
    const float* mg_w    = (const float*)d_in[10];
    const float* mg_b    = (const float*)d_in[11];
    const float* ln_g    = (const float*)d_in[12];
    const float* ln_b    = (const float*)d_in[13];
    const float* gw      = (const float*)d_in[14];
    const float* gb      = (const float*)d_in[15];
    const float* ew1     = (const float*)d_in[16];
    const float* eb1     = (const float*)d_in[17];
    const float* ew2     = (const float*)d_in[18];
    const float* eb2     = (const float*)d_in[19];
    const float* q1w     = (const float*)d_in[20];
    const float* q1b     = (const float*)d_in[21];
    const float* q2w     = (const float*)d_in[22];
    const float* q2b     = (const float*)d_in[23];
    const float* errw    = (const float*)d_in[24];
    const float* errb    = (const float*)d_in[25];
    const float* ag1w    = (const float*)d_in[26];
    const float* ag1b    = (const float*)d_in[27];
    const float* ag2w    = (const float*)d_in[28];
    const float* ag2b    = (const float*)d_in[29];
    const float* pscale  = (const float*)d_in[30];
    const float* head_w  = (const float*)d_in[31];
    const float* head_b  = (const float*)d_in[32];
    float* out = (float*)d_out;
    float* ws  = (float*)d_ws;

    const long NC = (long)NTOK * CDIM; // 1,048,576
    float* X0   = ws;
    float* X1   = ws + NC;
    float* RET  = ws + 2 * NC;
    float* XCAT = ws + 3 * NC;       // [N,2C]
    float* QKV  = ws + 5 * NC;       // [N,3C]
    float* OUTS = ws + 8 * NC;       // [N,2C]
    float* EN   = ws + 10 * NC;      // [N,256]
    float* SM   = ws + 10 * NC + NC / 2;
    float* PART = SM;
    float* HMEAN= SM + 16384;
    float* AWARE= SM + 17408;
    float* QUAL = SM + 17472;
    float* WV   = SM + 19520;
    int*   EIDX = (int*)(SM + 23616);
    int*   OFFI = (int*)(SM + 27712);   // 16 ints
    int*   LIST = (int*)(SM + 27728);   // 5120 ints
    int*   POSMAP = (int*)(SM + 32848); // 4096 ints
    float* R      = ws + 11 * NC;
    __bf16* PRIORB = (__bf16*)R;     // [16][1024][1024] bf16 = 8*NC floats
    float* Z      = R;
    float* XN     = R + NC;
    float* REASON = R + 2 * NC;
    float* INTRO  = R + 3 * NC;
    float* XQ     = R + 4 * NC;
    float* GATEB  = R + 5 * NC;
    __bf16* EHB   = (__bf16*)(R + 6 * NC); // [5120,1024] bf16
    float* EYS    = R + 9 * NC;            // [5120,512] f32
    float* Q1B    = R + 12 * NC;     // [N,2048]

    // bf16 region after 27*NC floats
    __bf16* bfw = (__bf16*)(ws + 27 * NC);
    __bf16* WB_mp   = bfw;                       // 512*1024
    __bf16* WB_qkv  = bfw + 524288;              // 4 * 1536*512
    __bf16* WB_mg   = bfw + 3670016;             // 2 * 512*1024
    __bf16* WB_q1   = bfw + 4718592;             // 2 * 2048*512
    __bf16* WB_err  = bfw + 6815744;             // 2 * 512*512
    __bf16* WB_ag1  = bfw + 7340032;             // 2048*1024
    __bf16* WB_ag2  = bfw + 9437184;             // 512*2048
    __bf16* WB_memn = bfw + 10485760;            // 256*512
    __bf16* WB_memt = bfw + 10616832;            // 512*256
    __bf16* WB_head = bfw + 10747904;            // 32000*512
    __bf16* ABF     = bfw + 27131904;            // up to 2048*2048
    __bf16* WB_e1   = bfw + 31326208;            // 16 * 1024*512
    __bf16* WB_e2   = bfw + 39714816;            // 16 * 512*1024
    // attention bf16 scratch lives inside ABF (3M of 4M elems)
    __bf16* QKB = ABF;                 // [16][1024][64]
    __bf16* KB  = ABF + 1048576;       // [16][1024][64]
    __bf16* VTB = ABF + 2097152;       // [16][64][1024]

    auto wtransN = [&](const float* W, __bf16* Wt, int K, int N, int cnt, long sW, long sD) {
        wtrans_k<<<dim3(N / 64, K / 64, cnt), 256, 0, stream>>>(W, Wt, K, N, sW, sD);
    };
    auto gemm = [&](const float* Asrc, int lda, const __bf16* B, float* C_, int ldc,
                    const float* bias, const float* res, int ldres, float alpha,
                    int Nn, int K, int act) {
        cvta_k<<<NTOK, 256, 0, stream>>>(Asrc, lda, K, ABF);
        gemm_bf16<<<dim3(Nn / 128, NTOK / 128), 256, 0, stream>>>(
            ABF, B, C_, ldc, bias, res, ldres, alpha, K, act);
    };

    // ---- weight conversion (same work every call; graph-safe) ----
    wtransN(mp_w, WB_mp, 1024, 512, 1, 0, 0);
    wtransN(qkv_w, WB_qkv, 512, 1536, 4, 512 * 1536, 1536 * 512);
    wtransN(mg_w, WB_mg, 1024, 512, 2, 1024 * 512, 512 * 1024);
    wtransN(q1w, WB_q1, 512, 2048, 2, 512 * 2048, 2048 * 512);
    wtransN(errw, WB_err, 512, 512, 2, 512 * 512, 512 * 512);
    wtransN(ew1, WB_e1, 512, 1024, 16, 524288, 524288);
    wtransN(ew2, WB_e2, 1024, 512, 16, 524288, 524288);
    wtransN(ag1w, WB_ag1, 1024, 2048, 1, 0, 0);
    wtransN(ag2w, WB_ag2, 2048, 512, 1, 0, 0);
    wtransN(head_w, WB_head, 512, VDIM, 1, 0, 0);
    wtransN(mem, WB_memt, 256, 512, 1, 0, 0);                // mem^T [512,256]
    cvta_k<<<256, 256, 0, stream>>>(mem, 512, 512, WB_memn); // mem [256,512] as [N,K]

    // ---- embedding + memory bank ----
    embed_k<<<NTOK, 256, 0, stream>>>(ids, embed_w, X0);
    gemm(X0, 512, WB_memn, EN, 256, nullptr, nullptr, 0, 1.f, 256, 512, 0);
    smrows_k<<<NTOK, 256, 0, stream>>>(EN);
    gemm(EN, 256, WB_memt, RET, 512, nullptr, nullptr, 0, 1.f, 512, 256, 0);
    concat_k<<<4096, 256, 0, stream>>>(X0, RET, XCAT);
    gemm(XCAT, 1024, WB_mp, X0, 512, mp_b, nullptr, 0, 1.f, 512, 1024, 0);

    float* xcur = X0;
    float* xalt = X1;
    for (int l = 0; l < 2; ++l) {
        for (int p = 0; p < 2; ++p) {
            const int lp = l * 2 + p;
            const float* hptr = (p == 0) ? xcur : OUTS;
            const int hlda = (p == 0) ? 512 : 1024;
            gemm(hptr, hlda, WB_qkv + (long)lp * 1536 * 512, QKV, 1536,
                 qkv_b + (long)lp * 1536, nullptr, 0, 1.f, 1536, 512, 0);
            meanp_k<<<256, 64, 0, stream>>>(hptr, hlda, PART);
            meanr_k<<<4, 256, 0, stream>>>(PART, HMEAN);
            aware_k<<<1, 64, 0, stream>>>(HMEAN, aw_w, aw_b, lp, AWARE);
            qkvprep_k<<<256, 256, 0, stream>>>(QKV, dscale, lp, AWARE, QKB, KB, VTB);
            attn2_k<<<512, 256, 0, stream>>>(QKB, KB, VTB, PRIORB,
                                             (p == 1) ? 1 : 0, OUTS, p * CDIM);
        }
        gemm(OUTS, 1024, WB_mg + (long)l * 512 * 1024, Z, 512, mg_b + (long)l * 512,
             xcur, 512, 1.f, 512, 1024, 0);
        ln_k<<<NTOK, 256, 0, stream>>>(Z, ln_g + (long)l * 512, ln_b + (long)l * 512, XN);
        gate_k<<<NTOK, 64, 0, stream>>>(XN, gw, gb, l, WV, EIDX);
        route_k<<<1, 256, 0, stream>>>(EIDX, OFFI, LIST, POSMAP);
        cvta_k<<<NTOK, 256, 0, stream>>>(XN, 512, 512, ABF);
        moe_g1_k<<<dim3(8, 40), 256, 0, stream>>>(ABF, WB_e1 + (long)l * 8 * 524288,
                eb1 + (long)l * 8192, OFFI, LIST, EHB);
        moe_g2_k<<<dim3(4, 40), 256, 0, stream>>>(EHB, WB_e2 + (long)l * 8 * 524288,
                eb2 + (long)l * 4096, OFFI, EYS);
        reason2_k<<<4096, 256, 0, stream>>>(XN, EYS, WV, POSMAP, REASON);
        gemm(xcur, 512, WB_q1 + (long)l * 2048 * 512, Q1B, 2048, q1b + (long)l * 2048,
             nullptr, 0, 1.f, 2048, 512, 1);
        qual_k<<<NTOK, 256, 0, stream>>>(Q1B, q2w, q2b, l, QUAL);
        xq_k<<<4096, 256, 0, stream>>>(xcur, QUAL, XQ);
        gemm(XQ, 512, WB_err + (long)l * 512 * 512, INTRO, 512, errb + (long)l * 512,
             xcur, 512, 0.3f, 512, 512, 0);
        concat_k<<<4096, 256, 0, stream>>>(REASON, INTRO, XCAT);
        gemm(XCAT, 1024, WB_ag1, Q1B, 2048, ag1b, nullptr, 0, 1.f, 2048, 1024, 1);
        gemm(Q1B, 2048, WB_ag2, GATEB, 512, ag2b, nullptr, 0, 1.f, 512, 2048, 2);
        final_k<<<4096, 256, 0, stream>>>(REASON, GATEB, pscale, INTRO, xalt);
        float* tmp = xcur; xcur = xalt; xalt = tmp;
    }
    // ---- head ----
    gemm(xcur, 512, WB_head, out, VDIM, head_b, nullptr, 0, 1.f, VDIM, 512, 0);
}

// Round 3
// 1679.397 us; speedup vs baseline: 2.8240x; 1.0094x over previous
//
#include <hip/hip_runtime.h>

// ConsciousTransformer forward. Round 5: (1) gemm_bf16 1-D grid, m-fastest per
// XCD chunk + bijective XCD swizzle (B-panel L2 reuse; head GEMM was re-fetching
// B ~8x). (2) All cvta_k conversions removed: producers emit bf16 shadows,
// GEMM epilogue can write bf16 (Cb) and A takes an lda.
// Dims: C=512, V=32000, L=2, P=2, E=8, HM=1024, H=8, M=256, B=2, T=1024, N=B*T=2048

#define NTOK 2048
#define CDIM 512
#define TLEN 1024
#define NB 2
#define NH 8
#define VDIM 32000

typedef __attribute__((ext_vector_type(4))) float f32x4;
typedef __attribute__((ext_vector_type(8))) __bf16 bf16x8;

#define AS1 __attribute__((address_space(1)))
#define AS3 __attribute__((address_space(3)))

__device__ __forceinline__ void g2lds16(const void* g, void* l) {
    __builtin_amdgcn_global_load_lds((const AS1 void*)g, (AS3 void*)l, 16, 0, 0);
}

// ---------------- bf16 MFMA GEMM: C = res + alpha*act(A@B^T + bias) ----------------
// A [M,lda] bf16 (first K cols), B [N,K] bf16 packed, C_ [M,N] fp32 (opt),
// Cb [M,N] bf16 (opt). act: 0=none, 1=silu, 2=tanh. M=2048 fixed (16 m-blocks),
// N mult of 128; K mult of 32. 1-D grid = 16*nbn, m-fastest within XCD chunk.
__global__ __launch_bounds__(256) void gemm_bf16(
    const __bf16* __restrict__ A, int lda,
    const __bf16* __restrict__ B,
    float* __restrict__ C_, int ldc,
    __bf16* __restrict__ Cb, int ldcb,
    const float* __restrict__ bias,
    const float* __restrict__ res, int ldres, float alpha,
    int K, int act)
{
    __shared__ __bf16 As[128 * 32];
    __shared__ __bf16 Bs[128 * 32];
    const int tid = threadIdx.x;
    const int w = tid >> 6, lane = tid & 63;
    // bijective XCD swizzle (m204) then m-fastest decomposition
    const int nwg = gridDim.x;
    const int q = nwg >> 3, r = nwg & 7;
    const int xcd = blockIdx.x & 7, ii = blockIdx.x >> 3;
    const int swz = (xcd < r) ? xcd * (q + 1) + ii : r * (q + 1) + (xcd - r) * q + ii;
    const int m0 = (swz & 15) * 128, n0 = (swz >> 4) * 128;
    const int wr = (w >> 1) * 64, wc = (w & 1) * 64;
    f32x4 acc[4][4] = {};
    const int mrow = lane & 15, kq = (lane >> 4) * 8;
    for (int k0 = 0; k0 < K; k0 += 32) {
#pragma unroll
        for (int i = 0; i < 2; ++i) {
            const int boff = w * 2048 + i * 1024 + lane * 16; // byte off in 128x32 bf16 tile
            const int row = boff >> 6;        // 64 B per row
            const int ke = (boff & 63) >> 1;  // bf16 elem within row
            g2lds16(A + (long)(m0 + row) * lda + k0 + ke, (char*)As + (boff - lane * 16));
            g2lds16(B + (long)(n0 + row) * K + k0 + ke, (char*)Bs + (boff - lane * 16));
        }
        __syncthreads();
        bf16x8 af[4], bfr[4];
#pragma unroll
        for (int i = 0; i < 4; ++i)
            af[i] = *(const bf16x8*)(As + (wr + i * 16 + mrow) * 32 + kq);
#pragma unroll
        for (int j = 0; j < 4; ++j)
            bfr[j] = *(const bf16x8*)(Bs + (wc + j * 16 + mrow) * 32 + kq);
#pragma unroll
        for (int i = 0; i < 4; ++i)
#pragma unroll
            for (int j = 0; j < 4; ++j)
                acc[i][j] = __builtin_amdgcn_mfma_f32_16x16x32_bf16(af[i], bfr[j], acc[i][j], 0, 0, 0);
        __syncthreads();
    }
    const int col_l = lane & 15, row_l = (lane >> 4) * 4;
#pragma unroll
    for (int i = 0; i < 4; ++i)
#pragma unroll
        for (int j = 0; j < 4; ++j) {
            const int n = n0 + wc + j * 16 + col_l;
            const float bv = bias ? bias[n] : 0.f;
#pragma unroll
            for (int r2 = 0; r2 < 4; ++r2) {
                const int m = m0 + wr + i * 16 + row_l + r2;
                float v = acc[i][j][r2] + bv;
                if (act == 1) v = v / (1.f + __expf(-v));
                else if (act == 2) v = tanhf(v);
                v *= alpha;
                if (res) v += res[(long)m * ldres + n];
                if (C_) C_[(long)m * ldc + n] = v;
                if (Cb) Cb[(long)m * ldcb + n] = (__bf16)v;
            }
        }
}

// ---------------- MoE routing: per-expert 128-aligned segments ----------------
__global__ __launch_bounds__(256) void route_k(const int* __restrict__ eidx,
                                               int* __restrict__ offi,
                                               int* __restrict__ list,
                                               int* __restrict__ posmap)
{
    __shared__ int cnt[8], fill[8], seg[9];
    const int t = threadIdx.x;
    if (t < 8) cnt[t] = 0;
    __syncthreads();
    for (int i = t; i < NTOK * 2; i += 256) atomicAdd(&cnt[eidx[i]], 1);
    __syncthreads();
    if (t == 0) {
        int run = 0;
        for (int e = 0; e < 8; ++e) {
            seg[e] = run;
            run += (cnt[e] + 127) & ~127;
        }
        seg[8] = run;
    }
    __syncthreads();
    if (t < 8) fill[t] = seg[t];
    if (t < 9) offi[t] = seg[t];
    __syncthreads();
    for (int i = t; i < NTOK * 2; i += 256) {
        const int e = eidx[i];
        const int g = atomicAdd(&fill[e], 1);
        list[g] = i;
        posmap[i] = g;
    }
    __syncthreads();
#pragma unroll
    for (int e = 0; e < 8; ++e)
        for (int g = seg[e] + cnt[e] + t; g < seg[e + 1]; g += 256) list[g] = 0;
}

// ---------------- MoE mlp1: gathered-A GEMM + swiglu, bf16 out ----------------
__global__ __launch_bounds__(256) void moe_g1_k(
    const __bf16* __restrict__ A,
    const __bf16* __restrict__ Bw,
    const float* __restrict__ eb1l,
    const int* __restrict__ offi,
    const int* __restrict__ list,
    __bf16* __restrict__ EHB)
{
    const int m0 = blockIdx.y * 128;
    if (m0 >= offi[8]) return;
    int e = 0;
    while (e < 7 && offi[e + 1] <= m0) ++e;   // segments are 128-aligned
    const __bf16* B = Bw + (long)e * (1024 * 512);
    const float* bias = eb1l + e * 1024;
    __shared__ __bf16 As[128 * 32];
    __shared__ __bf16 Bs[128 * 32];
    __shared__ int toks[128];
    const int tid = threadIdx.x;
    if (tid < 128) toks[tid] = list[m0 + tid] >> 1;
    __syncthreads();
    const int w = tid >> 6, lane = tid & 63;
    const int n0 = blockIdx.x * 128;
    const int wr = (w >> 1) * 64, wc = (w & 1) * 64;
    f32x4 acc[4][4] = {};
    const int mrow = lane & 15, kq = (lane >> 4) * 8;
    for (int k0 = 0; k0 < 512; k0 += 32) {
#pragma unroll
        for (int i = 0; i < 2; ++i) {
            const int boff = w * 2048 + i * 1024 + lane * 16;
            const int row = boff >> 6;
            const int ke = (boff & 63) >> 1;
            g2lds16(A + (long)toks[row] * 512 + k0 + ke, (char*)As + (boff - lane * 16));
            g2lds16(B + (long)(n0 + row) * 512 + k0 + ke, (char*)Bs + (boff - lane * 16));
        }
        __syncthreads();
        bf16x8 af[4], bfr[4];
#pragma unroll
        for (int i = 0; i < 4; ++i)
            af[i] = *(const bf16x8*)(As + (wr + i * 16 + mrow) * 32 + kq);
#pragma unroll
        for (int j = 0; j < 4; ++j)
            bfr[j] = *(const bf16x8*)(Bs + (wc + j * 16 + mrow) * 32 + kq);
#pragma unroll
        for (int i = 0; i < 4; ++i)
#pragma unroll
            for (int j = 0; j < 4; ++j)
                acc[i][j] = __builtin_amdgcn_mfma_f32_16x16x32_bf16(af[i], bfr[j], acc[i][j], 0, 0, 0);
        __syncthreads();
    }
    const int col_l = lane & 15, row_l = (lane >> 4) * 4;
#pragma unroll
    for (int i = 0; i < 4; ++i)
#pragma unroll
        for (int j = 0; j < 4; ++j) {
            const int n = n0 + wc + j * 16 + col_l;
            const float bv = bias[n];
#pragma unroll
            for (int r = 0; r < 4; ++r) {
                const int g = m0 + wr + i * 16 + row_l + r;
                const float v = acc[i][j][r] + bv;
                EHB[(long)g * 1024 + n] = (__bf16)(v * v / (1.f + __expf(-v)));
            }
        }
}

// ---------------- MoE mlp2: segment-contiguous GEMM, f32 out ----------------
__global__ __launch_bounds__(256) void moe_g2_k(
    const __bf16* __restrict__ A,
    const __bf16* __restrict__ Bw,
    const float* __restrict__ eb2l,
    const int* __restrict__ offi,
    float* __restrict__ EYS)
{
    const int m0 = blockIdx.y * 128;
    if (m0 >= offi[8]) return;
    int e = 0;
    while (e < 7 && offi[e + 1] <= m0) ++e;
    const __bf16* B = Bw + (long)e * (512 * 1024);
    const float* bias = eb2l + e * 512;
    __shared__ __bf16 As[128 * 32];
    __shared__ __bf16 Bs[128 * 32];
    const int tid = threadIdx.x;
    const int w = tid >> 6, lane = tid & 63;
    const int n0 = blockIdx.x * 128;
    const int wr = (w >> 1) * 64, wc = (w & 1) * 64;
    f32x4 acc[4][4] = {};
    const int mrow = lane & 15, kq = (lane >> 4) * 8;
    for (int k0 = 0; k0 < 1024; k0 += 32) {
#pragma unroll
        for (int i = 0; i < 2; ++i) {
            const int boff = w * 2048 + i * 1024 + lane * 16;
            const int row = boff >> 6;
            const int ke = (boff & 63) >> 1;
            g2lds16(A + (long)(m0 + row) * 1024 + k0 + ke, (char*)As + (boff - lane * 16));
            g2lds16(B + (long)(n0 + row) * 1024 + k0 + ke, (char*)Bs + (boff - lane * 16));
        }
        __syncthreads();
        bf16x8 af[4], bfr[4];
#pragma unroll
        for (int i = 0; i < 4; ++i)
            af[i] = *(const bf16x8*)(As + (wr + i * 16 + mrow) * 32 + kq);
#pragma unroll
        for (int j = 0; j < 4; ++j)
            bfr[j] = *(const bf16x8*)(Bs + (wc + j * 16 + mrow) * 32 + kq);
#pragma unroll
        for (int i = 0; i < 4; ++i)
#pragma unroll
            for (int j = 0; j < 4; ++j)
                acc[i][j] = __builtin_amdgcn_mfma_f32_16x16x32_bf16(af[i], bfr[j], acc[i][j], 0, 0, 0);
        __syncthreads();
    }
    const int col_l = lane & 15, row_l = (lane >> 4) * 4;
#pragma unroll
    for (int i = 0; i < 4; ++i)
#pragma unroll
        for (int j = 0; j < 4; ++j) {
            const int n = n0 + wc + j * 16 + col_l;
            const float bv = bias[n];
#pragma unroll
            for (int r = 0; r < 4; ++r) {
                const int g = m0 + wr + i * 16 + row_l + r;
                EYS[(long)g * 512 + n] = acc[i][j][r] + bv;
            }
        }
}

// ---------------- reason = xn + 0.5*(w0*ey[pos0] + w1*ey[pos1]) ----------------
__global__ __launch_bounds__(256) void reason2_k(const float* __restrict__ xn,
                                                 const float* __restrict__ EYS,
                                                 const float* __restrict__ wv,
                                                 const int* __restrict__ posmap,
                                                 float* __restrict__ reason)
{
    const long i = (long)blockIdx.x * 256 + threadIdx.x;
    const long n = i >> 9;
    const int c = (int)(i & 511);
    const int g0 = posmap[n * 2], g1 = posmap[n * 2 + 1];
    const float v = wv[n * 2] * EYS[(long)g0 * 512 + c] + wv[n * 2 + 1] * EYS[(long)g1 * 512 + c];
    reason[i] = xn[i] + 0.5f * v;
}

// ---------------- weight transpose+convert (batched): W [K,N] f32 -> Wt [N,K] bf16 ----------------
__global__ __launch_bounds__(256) void wtrans_k(const float* __restrict__ W0,
                                                __bf16* __restrict__ Wt0, int K, int N,
                                                long sW, long sD)
{
    const float* W = W0 + (long)blockIdx.z * sW;
    __bf16* Wt = Wt0 + (long)blockIdx.z * sD;
    __shared__ float tile[64][65];
    const int k0 = blockIdx.y * 64, n0 = blockIdx.x * 64;
    const int t = threadIdx.x;
#pragma unroll
    for (int i = 0; i < 4; ++i) {
        const int r = (t >> 4) + i * 16;
        const int c = (t & 15) * 4;
        float4 v = *(const float4*)(W + (long)(k0 + r) * N + n0 + c);
        tile[r][c] = v.x; tile[r][c + 1] = v.y; tile[r][c + 2] = v.z; tile[r][c + 3] = v.w;
    }
    __syncthreads();
#pragma unroll
    for (int i = 0; i < 4; ++i) {
        const int rr = (t >> 4) + i * 16;   // n
        const int cc = (t & 15) * 4;        // k
        __bf16* o = Wt + (long)(n0 + rr) * K + k0 + cc;
        o[0] = (__bf16)tile[cc][rr];
        o[1] = (__bf16)tile[cc + 1][rr];
        o[2] = (__bf16)tile[cc + 2][rr];
        o[3] = (__bf16)tile[cc + 3][rr];
    }
}

// ---------------- f32 -> bf16 convert (one-time, mem) ----------------
__global__ __launch_bounds__(256) void cvta_k(const float* __restrict__ src, int lda, int K,
                                              __bf16* __restrict__ dst)
{
    const int row = blockIdx.x, t = threadIdx.x;
    const float* s = src + (long)row * lda;
    __bf16* d = dst + (long)row * K;
    for (int c = t * 4; c < K; c += 1024) {
        float4 v = *(const float4*)(s + c);
        d[c] = (__bf16)v.x; d[c + 1] = (__bf16)v.y; d[c + 2] = (__bf16)v.z; d[c + 3] = (__bf16)v.w;
    }
}

// ---------------- embedding gather (f32 + bf16 shadow) ----------------
__global__ __launch_bounds__(256) void embed_k(const int* __restrict__ ids,
                                               const float* __restrict__ ew,
                                               float* __restrict__ x,
                                               __bf16* __restrict__ xb)
{
    const int n = blockIdx.x, t = threadIdx.x;
    const long r = (long)ids[n] * CDIM;
    const float v0 = ew[r + t], v1 = ew[r + 256 + t];
    x[(long)n * CDIM + t]       = v0;
    x[(long)n * CDIM + 256 + t] = v1;
    xb[(long)n * CDIM + t]       = (__bf16)v0;
    xb[(long)n * CDIM + 256 + t] = (__bf16)v1;
}

// ---------------- row softmax (width 256) -> bf16 out ----------------
__global__ __launch_bounds__(256) void smrows_k(const float* __restrict__ a,
                                                __bf16* __restrict__ ob)
{
    const int n = blockIdx.x, t = threadIdx.x;
    __shared__ float rs[256];
    float v = a[(long)n * 256 + t];
    rs[t] = v; __syncthreads();
    for (int o = 128; o; o >>= 1) { if (t < o) rs[t] = fmaxf(rs[t], rs[t + o]); __syncthreads(); }
    const float m = rs[0]; __syncthreads();
    const float e = __expf(v - m);
    rs[t] = e; __syncthreads();
    for (int o = 128; o; o >>= 1) { if (t < o) rs[t] += rs[t + o]; __syncthreads(); }
    ob[(long)n * 256 + t] = (__bf16)(e / rs[0]);
}

// ---------------- concat two f32 [N,C] -> bf16 [N,2C] ----------------
__global__ __launch_bounds__(256) void concat_bf_k(const float* __restrict__ a,
                                                   const float* __restrict__ b,
                                                   __bf16* __restrict__ o)
{
    const long i = (long)blockIdx.x * 256 + threadIdx.x;
    const long n = i >> 9;
    const int c = (int)(i & 511);
    o[n * 1024 + c]       = (__bf16)a[i];
    o[n * 1024 + 512 + c] = (__bf16)b[i];
}

// ---------------- mean over T (partial + reduce) ----------------
__global__ __launch_bounds__(64) void meanp_k(const float* __restrict__ A, int lda,
                                              float* __restrict__ part)
{
    const int bid = blockIdx.x;
    const int ts = bid & 15;
    const int cg = (bid >> 4) & 7;
    const int b  = bid >> 7;
    const int c  = cg * 64 + threadIdx.x;
    const float* p = A + ((long)b * TLEN + ts * 64) * lda + c;
    float s = 0.f;
    for (int t = 0; t < 64; ++t) s += p[(long)t * lda];
    part[(long)ts * 1024 + b * 512 + c] = s;
}
__global__ __launch_bounds__(256) void meanr_k(const float* __restrict__ part,
                                               float* __restrict__ hm)
{
    const int i = blockIdx.x * 256 + threadIdx.x;
    float s = 0.f;
    for (int ts = 0; ts < 16; ++ts) s += part[ts * 1024 + i];
    hm[i] = s * (1.f / 1024.f);
}

// ---------------- awareness ----------------
__global__ __launch_bounds__(64) void aware_k(const float* __restrict__ hm,
                                              const float* __restrict__ aw_w,
                                              const float* __restrict__ aw_b,
                                              int lp, float* __restrict__ out)
{
    const int t = threadIdx.x;
    if (t < NB * NH) {
        const int b = t >> 3, hh = t & 7;
        const float* W = aw_w + (long)lp * CDIM * NH;
        const float* x = hm + b * CDIM;
        float s = aw_b[lp * NH + hh];
        for (int c = 0; c < CDIM; ++c) s += x[c] * W[c * NH + hh];
        out[t] = s;
    }
}

// ---------------- per-phase attention prep: fp32 QKV -> bf16 Q*scale, K, V^T ----------------
__global__ __launch_bounds__(256) void qkvprep_k(
    const float* __restrict__ qkv,
    const float* __restrict__ dscale, int lp,
    const float* __restrict__ aware,
    __bf16* __restrict__ QKB, __bf16* __restrict__ KB, __bf16* __restrict__ VTB)
{
    const int bh = blockIdx.x >> 4;
    const int tc = blockIdx.x & 15;
    const int b = bh >> 3, h = bh & 7;
    const int tid = threadIdx.x;
    const float sc = dscale[lp] * aware[bh];
    __shared__ float vt[64][68];
    const int row = tid >> 2, c0 = (tid & 3) * 16;
    const long rbase = ((long)(b * 1024 + tc * 64 + row)) * 1536 + h * 64 + c0;
    {
        bf16x8 qo[2], ko[2];
#pragma unroll
        for (int i = 0; i < 2; ++i)
#pragma unroll
            for (int jj = 0; jj < 2; ++jj) {
                const float4 qq = *(const float4*)(qkv + rbase + (i * 2 + jj) * 4);
                const float4 kk = *(const float4*)(qkv + rbase + 512 + (i * 2 + jj) * 4);
                qo[i][jj * 4 + 0] = (__bf16)(qq.x * sc);
                qo[i][jj * 4 + 1] = (__bf16)(qq.y * sc);
                qo[i][jj * 4 + 2] = (__bf16)(qq.z * sc);
                qo[i][jj * 4 + 3] = (__bf16)(qq.w * sc);
                ko[i][jj * 4 + 0] = (__bf16)kk.x;
                ko[i][jj * 4 + 1] = (__bf16)kk.y;
                ko[i][jj * 4 + 2] = (__bf16)kk.z;
                ko[i][jj * 4 + 3] = (__bf16)kk.w;
            }
        const long obase = (long)bh * 65536 + (long)(tc * 64 + row) * 64 + c0;
        *(bf16x8*)(QKB + obase) = qo[0];
        *(bf16x8*)(QKB + obase + 8) = qo[1];
        *(bf16x8*)(KB + obase) = ko[0];
        *(bf16x8*)(KB + obase + 8) = ko[1];
    }
    {
        const long vbase = ((long)(b * 1024 + tc * 64 + row)) * 1536 + 1024 + h * 64 + c0;
#pragma unroll
        for (int i = 0; i < 4; ++i) {
            const float4 v = *(const float4*)(qkv + vbase + i * 4);
            vt[row][c0 + i * 4 + 0] = v.x;
            vt[row][c0 + i * 4 + 1] = v.y;
            vt[row][c0 + i * 4 + 2] = v.z;
            vt[row][c0 + i * 4 + 3] = v.w;
        }
    }
    __syncthreads();
    {
        const int d = row;                 // 0..63
        const int s0 = c0;                 // 0,16,32,48
        bf16x8 o0, o1;
#pragma unroll
        for (int j = 0; j < 8; ++j) o0[j] = (__bf16)vt[s0 + j][d];
#pragma unroll
        for (int j = 0; j < 8; ++j) o1[j] = (__bf16)vt[s0 + 8 + j][d];
        __bf16* dst = VTB + (long)bh * 65536 + (long)d * 1024 + tc * 64 + s0;
        *(bf16x8*)dst = o0;
        *(bf16x8*)(dst + 8) = o1;
    }
}

// ---------------- MFMA attention: 32 Q-rows per block, full-row softmax + prior ----------------
#define RB 32
__global__ __launch_bounds__(256) void attn2_k(
    const __bf16* __restrict__ QKB,
    const __bf16* __restrict__ KB,
    const __bf16* __restrict__ VTB,
    __bf16* __restrict__ prior,
    int use_prior,
    float* __restrict__ outs, __bf16* __restrict__ outsb, int out_off)
{
    __shared__ __align__(16) __bf16 qs[RB * 64];
    __shared__ __align__(16) __bf16 kv[2][128 * 64];
    __shared__ __align__(16) __bf16 ss[RB * 1024];
    const int tid = threadIdx.x;
    const int w = tid >> 6, lane = tid & 63;
    const int rb = blockIdx.x & 31;
    const int bh = blockIdx.x >> 5;
    const int b = bh >> 3, h = bh & 7;
    const int t0 = rb * RB;
    const long qkbase = (long)bh * 65536;
    const int mrow = lane & 15, kq = (lane >> 4) * 8;

    {
        const int row = tid >> 3, gl = tid & 7;
        const int gs = gl ^ (row & 7);
        g2lds16(QKB + qkbase + (long)(t0 + row) * 64 + gs * 8,
                (char*)qs + tid * 16 - lane * 16);
    }
    {
        for (int it = 0; it < 4; ++it) {
            const int idx = it * 256 + tid;
            const int row = idx >> 3, gl = idx & 7;
            const int gs = gl ^ (row & 7);
            g2lds16(KB + qkbase + (long)row * 64 + gs * 8,
                    (char*)kv[0] + idx * 16 - lane * 16);
        }
        __syncthreads();
        int buf = 0;
        const int ntb = w * 2;
        for (int c = 0; c < 8; ++c) {
            if (c < 7) {
                const int s0n = (c + 1) * 128;
                for (int it = 0; it < 4; ++it) {
                    const int idx = it * 256 + tid;
                    const int row = idx >> 3, gl = idx & 7;
                    const int gs = gl ^ (row & 7);
                    g2lds16(KB + qkbase + (long)(s0n + row) * 64 + gs * 8,
                            (char*)kv[buf ^ 1] + idx * 16 - lane * 16);
                }
            }
            f32x4 accs[2][2] = {};
#pragma unroll
            for (int k0 = 0; k0 < 64; k0 += 32) {
                bf16x8 aq[2], bk[2];
#pragma unroll
                for (int mt = 0; mt < 2; ++mt) {
                    const int r = mt * 16 + mrow;
                    const int col = k0 + kq;
                    aq[mt] = *(const bf16x8*)(qs + r * 64 + (((col >> 3) ^ (r & 7)) << 3));
                }
#pragma unroll
                for (int j = 0; j < 2; ++j) {
                    const int nl = (ntb + j) * 16 + mrow;
                    const int col = k0 + kq;
                    bk[j] = *(const bf16x8*)(kv[buf] + nl * 64 + (((col >> 3) ^ (nl & 7)) << 3));
                }
#pragma unroll
                for (int mt = 0; mt < 2; ++mt)
#pragma unroll
                    for (int j = 0; j < 2; ++j)
                        accs[mt][j] = __builtin_amdgcn_mfma_f32_16x16x32_bf16(aq[mt], bk[j], accs[mt][j], 0, 0, 0);
            }
            const int col_l = lane & 15, row_l = (lane >> 4) * 4;
#pragma unroll
            for (int mt = 0; mt < 2; ++mt)
#pragma unroll
                for (int j = 0; j < 2; ++j) {
                    const int ccol = c * 128 + (ntb + j) * 16 + col_l;
#pragma unroll
                    for (int r = 0; r < 4; ++r) {
                        const int rr = mt * 16 + row_l + r;
                        ss[rr * 1024 + (((ccol >> 3) ^ (rr & 7)) << 3) + (ccol & 7)] = (__bf16)accs[mt][j][r];
                    }
                }
            __syncthreads();
            buf ^= 1;
        }
    }
    for (int it = 0; it < 4; ++it) {
        const int idx = it * 256 + tid;
        const int d = idx >> 4, gl = idx & 15;
        const int gs = gl ^ (d & 7);
        g2lds16(VTB + (long)bh * 65536 + (long)d * 1024 + gs * 8,
                (char*)kv[0] + idx * 16 - lane * 16);
    }
    {
        const int r = tid >> 3;
        const int li = tid & 7;
        const int rsw = r & 7;
        float mx = -1e30f;
        for (int j = 0; j < 16; ++j) {
            const int c = j * 64 + li * 8;
            bf16x8 v = *(const bf16x8*)(ss + r * 1024 + (((c >> 3) ^ rsw) << 3));
#pragma unroll
            for (int q = 0; q < 8; ++q) mx = fmaxf(mx, (float)v[q]);
        }
        mx = fmaxf(mx, __shfl_xor(mx, 1));
        mx = fmaxf(mx, __shfl_xor(mx, 2));
        mx = fmaxf(mx, __shfl_xor(mx, 4));
        float sum = 0.f;
        for (int j = 0; j < 16; ++j) {
            const int c = j * 64 + li * 8;
            __bf16* p = ss + r * 1024 + (((c >> 3) ^ rsw) << 3);
            bf16x8 v = *(const bf16x8*)p;
            bf16x8 e;
#pragma unroll
            for (int q = 0; q < 8; ++q) {
                const float ev = __expf((float)v[q] - mx);
                sum += ev;
                e[q] = (__bf16)ev;
            }
            *(bf16x8*)p = e;
        }
        sum += __shfl_xor(sum, 1);
        sum += __shfl_xor(sum, 2);
        sum += __shfl_xor(sum, 4);
        const float rinv = 1.f / sum;
        const long pbase = ((long)bh * 1024 + t0 + r) * 1024;
        for (int j = 0; j < 16; ++j) {
            const int c = j * 64 + li * 8;
            __bf16* p = ss + r * 1024 + (((c >> 3) ^ rsw) << 3);
            bf16x8 v = *(const bf16x8*)p;
            bf16x8 o;
            if (use_prior) {
                bf16x8 pr = *(const bf16x8*)(prior + pbase + c);
#pragma unroll
                for (int q = 0; q < 8; ++q)
                    o[q] = (__bf16)((float)v[q] * rinv + 0.3f * (float)pr[q]);
            } else {
#pragma unroll
                for (int q = 0; q < 8; ++q)
                    o[q] = (__bf16)((float)v[q] * rinv);
            }
            *(bf16x8*)p = o;
            *(bf16x8*)(prior + pbase + c) = o;
        }
    }
    __syncthreads();
    {
        f32x4 po[2] = {};
        int buf = 0;
        const int mt = w >> 1;
        const int ntb2 = (w & 1) * 2;
        for (int c = 0; c < 8; ++c) {
            if (c < 7) {
                const int s0n = (c + 1) * 128;
                for (int it = 0; it < 4; ++it) {
                    const int idx = it * 256 + tid;
                    const int d = idx >> 4, gl = idx & 15;
                    const int gs = gl ^ (d & 7);
                    g2lds16(VTB + (long)bh * 65536 + (long)d * 1024 + s0n + gs * 8,
                            (char*)kv[buf ^ 1] + idx * 16 - lane * 16);
                }
            }
#pragma unroll
            for (int ks = 0; ks < 4; ++ks) {
                const int r = mt * 16 + mrow;
                const int cola = c * 128 + ks * 32 + kq;
                bf16x8 pa = *(const bf16x8*)(ss + r * 1024 + (((cola >> 3) ^ (r & 7)) << 3));
                bf16x8 vb[2];
#pragma unroll
                for (int j = 0; j < 2; ++j) {
                    const int d = (ntb2 + j) * 16 + mrow;
                    const int colv = ks * 32 + kq;
                    vb[j] = *(const bf16x8*)(kv[buf] + d * 128 + (((colv >> 3) ^ (d & 7)) << 3));
                }
                po[0] = __builtin_amdgcn_mfma_f32_16x16x32_bf16(pa, vb[0], po[0], 0, 0, 0);
                po[1] = __builtin_amdgcn_mfma_f32_16x16x32_bf16(pa, vb[1], po[1], 0, 0, 0);
            }
            __syncthreads();
            buf ^= 1;
        }
        const int col_l = lane & 15, row_l = (lane >> 4) * 4;
#pragma unroll
        for (int j = 0; j < 2; ++j) {
            const int d = out_off + h * 64 + (ntb2 + j) * 16 + col_l;
#pragma unroll
            for (int r = 0; r < 4; ++r) {
                const int trow = t0 + mt * 16 + row_l + r;
                float v = po[j][r];
                v = v / (1.f + __expf(-v));
                const long oi = ((long)(b * 1024 + trow)) * 1024 + d;
                outs[oi] = v;
                outsb[oi] = (__bf16)v;
            }
        }
    }
}

// ---------------- layernorm over C=512 (f32 + bf16 shadow) ----------------
__global__ __launch_bounds__(256) void ln_k(const float* __restrict__ z,
                                            const float* __restrict__ g,
                                            const float* __restrict__ bb,
                                            float* __restrict__ xn,
                                            __bf16* __restrict__ xnb)
{
    const int n = blockIdx.x, t = threadIdx.x;
    __shared__ float rs[256], rq[256];
    const float v0 = z[(long)n * 512 + t];
    const float v1 = z[(long)n * 512 + 256 + t];
    rs[t] = v0 + v1;
    rq[t] = v0 * v0 + v1 * v1;
    __syncthreads();
    for (int o = 128; o; o >>= 1) {
        if (t < o) { rs[t] += rs[t + o]; rq[t] += rq[t + o]; }
        __syncthreads();
    }
    const float mu = rs[0] * (1.f / 512.f);
    const float var = rq[0] * (1.f / 512.f) - mu * mu;
    const float rstd = rsqrtf(var + 1e-5f);
    const float o0 = (v0 - mu) * rstd * g[t] + bb[t];
    const float o1 = (v1 - mu) * rstd * g[t + 256] + bb[t + 256];
    xn[(long)n * 512 + t]       = o0;
    xn[(long)n * 512 + 256 + t] = o1;
    xnb[(long)n * 512 + t]       = (__bf16)o0;
    xnb[(long)n * 512 + 256 + t] = (__bf16)o1;
}

// ---------------- MoE gate ----------------
__global__ __launch_bounds__(64) void gate_k(const float* __restrict__ xn,
                                             const float* __restrict__ gw,
                                             const float* __restrict__ gb,
                                             int l, float* __restrict__ wv,
                                             int* __restrict__ eidx)
{
    const int n = blockIdx.x, t = threadIdx.x;
    const int e = t & 7, ch = t >> 3;
    const float* W = gw + (long)l * CDIM * 8;
    float part = 0.f;
    for (int k = ch * 64; k < ch * 64 + 64; ++k) part += xn[(long)n * CDIM + k] * W[k * 8 + e];
    part += __shfl_xor(part, 8, 64);
    part += __shfl_xor(part, 16, 64);
    part += __shfl_xor(part, 32, 64);
    __shared__ float lg[8];
    if (t < 8) lg[t] = part + gb[l * 8 + t];
    __syncthreads();
    if (t == 0) {
        float m = lg[0];
        for (int i = 1; i < 8; ++i) m = fmaxf(m, lg[i]);
        float p[8], s = 0.f;
        for (int i = 0; i < 8; ++i) { p[i] = __expf(lg[i] - m); s += p[i]; }
        const float inv = 1.f / s;
        int i0 = 0;
        for (int i = 1; i < 8; ++i) if (p[i] > p[i0]) i0 = i;
        int i1 = (i0 == 0) ? 1 : 0;
        for (int i = 0; i < 8; ++i) { if (i == i0) continue; if (p[i] > p[i1]) i1 = i; }
        eidx[n * 2] = i0; eidx[n * 2 + 1] = i1;
        wv[n * 2] = p[i0] * inv; wv[n * 2 + 1] = p[i1] * inv;
    }
}

// ---------------- quality (bf16 input) ----------------
__global__ __launch_bounds__(256) void qual_k(const __bf16* __restrict__ t1,
                                              const float* __restrict__ q2w,
                                              const float* __restrict__ q2b,
                                              int l, float* __restrict__ qual)
{
    const int n = blockIdx.x, t = threadIdx.x;
    const float* W = q2w + (long)l * 2048;
    float s = 0.f;
    for (int k = t; k < 2048; k += 256) s += (float)t1[(long)n * 2048 + k] * W[k];
    __shared__ float rs[256];
    rs[t] = s; __syncthreads();
    for (int o = 128; o; o >>= 1) { if (t < o) rs[t] += rs[t + o]; __syncthreads(); }
    if (t == 0) {
        const float q = rs[0] + q2b[l];
        qual[n] = 1.f / (1.f + __expf(-q));
    }
}

// ---------------- xq = x_in * (1 - quality), bf16 out ----------------
__global__ __launch_bounds__(256) void xq_k(const float* __restrict__ x_in,
                                            const float* __restrict__ qual,
                                            __bf16* __restrict__ xqb)
{
    const long i = (long)blockIdx.x * 256 + threadIdx.x;
    const long n = i >> 9;
    xqb[i] = (__bf16)(x_in[i] * (1.f - qual[n]));
}

// ---------------- x = reason + gate*pscale*intro (f32 + bf16 shadow) ----------------
__global__ __launch_bounds__(256) void final_k(const float* __restrict__ reason,
                                               const float* __restrict__ gate,
                                               const float* __restrict__ pscale,
                                               const float* __restrict__ intro,
                                               float* __restrict__ xo,
                                               __bf16* __restrict__ xob)
{
    const long i = (long)blockIdx.x * 256 + threadIdx.x;
    const int c = (int)(i & 511);
    const float v = reason[i] + gate[i] * pscale[c] * intro[i];
    xo[i] = v;
    xob[i] = (__bf16)v;
}

// =======================================================================
extern "C" void kernel_launch(void* const* d_in, const int* in_sizes, int n_in,
                              void* d_out, int out_size, void* d_ws, size_t ws_size,
                              hipStream_t stream)
{
    (void)in_sizes; (void)n_in; (void)out_size; (void)ws_size;
    const int*   ids     = (const int*)  d_in[0];
    const float* embed_w = (const float*)d_in[1];
    const float* mem     = (const float*)d_in[2];
    const float* mp_w    = (const float*)d_in[3];
    const float* mp_b    = (const float*)d_in[4];
    const float* qkv_w   = (const float*)d_in[5];
    const float* qkv_b   = (const float*)d_in[6];
    const float* aw_w    = (const float*)d_in[7];
    const float* aw_b    = (const float*)d_in[8];
    const float* dscale  = (const float*)d_in[9];
    const float* mg_w    = (const float*)d_in[10];
    const float* mg_b    = (const float*)d_in[11];
    const float* ln_g    = (const float*)d_in[12];
    const float* ln_b    = (const float*)d_in[13];
    const float* gw      = (const float*)d_in[14];
    const float* gb      = (const float*)d_in[15];
    const float* ew1     = (const float*)d_in[16];
    const float* eb1     = (const float*)d_in[17];
    const float* ew2     = (const float*)d_in[18];
    const float* eb2     = (const float*)d_in[19];
    const float* q1w     = (const float*)d_in[20];
    const float* q1b     = (const float*)d_in[21];
    const float* q2w     = (const float*)d_in[22];
    const float* q2b     = (const float*)d_in[23];
    const float* errw    = (const float*)d_in[24];
    const float* errb    = (const float*)d_in[25];
    const float* ag1w    = (const float*)d_in[26];
    const float* ag1b    = (const float*)d_in[27];
    const float* ag2w    = (const float*)d_in[28];
    const float* ag2b    = (const float*)d_in[29];
    const float* pscale  = (const float*)d_in[30];
    const float* head_w  = (const float*)d_in[31];
    const float* head_b  = (const float*)d_in[32];
    float* out = (float*)d_out;
    float* ws  = (float*)d_ws;

    const long NC = (long)NTOK * CDIM; // 1,048,576
    float* X0   = ws;
    float* X1   = ws + NC;
    float* RET  = ws + 2 * NC;
    float* QKV  = ws + 5 * NC;       // [N,3C]
    float* OUTS = ws + 8 * NC;       // [N,2C]
    float* EN   = ws + 10 * NC;      // [N,256]
    float* SM   = ws + 10 * NC + NC / 2;
    float* PART = SM;
    float* HMEAN= SM + 16384;
    float* AWARE= SM + 17408;
    float* QUAL = SM + 17472;
    float* WV   = SM + 19520;
    int*   EIDX = (int*)(SM + 23616);
    int*   OFFI = (int*)(SM + 27712);   // 16 ints
    int*   LIST = (int*)(SM + 27728);   // 5120 ints
    int*   POSMAP = (int*)(SM + 32848); // 4096 ints
    float* R      = ws + 11 * NC;
    __bf16* PRIORB = (__bf16*)R;     // [16][1024][1024] bf16 = 8*NC floats (overlay)
    float* Z      = R;
    float* XN     = R + NC;
    float* REASON = R + 2 * NC;
    float* INTRO  = R + 3 * NC;
    float* GATEB  = R + 5 * NC;
    __bf16* EHB   = (__bf16*)(R + 6 * NC); // [5120,1024] bf16
    float* EYS    = R + 9 * NC;            // [5120,512] f32

    // bf16 region after 27*NC floats
    __bf16* bfw = (__bf16*)(ws + 27 * NC);
    __bf16* WB_mp   = bfw;                       // 512*1024
    __bf16* WB_qkv  = bfw + 524288;              // 4 * 1536*512
    __bf16* WB_mg   = bfw + 3670016;             // 2 * 512*1024
    __bf16* WB_q1   = bfw + 4718592;             // 2 * 2048*512
    __bf16* WB_err  = bfw + 6815744;             // 2 * 512*512
    __bf16* WB_ag1  = bfw + 7340032;             // 2048*1024
    __bf16* WB_ag2  = bfw + 9437184;             // 512*2048
    __bf16* WB_memn = bfw + 10485760;            // 256*512
    __bf16* WB_memt = bfw + 10616832;            // 512*256
    __bf16* WB_head = bfw + 10747904;            // 32000*512
    __bf16* QKB = bfw + 27131904;                // [16][1024][64]
    __bf16* KB  = QKB + 1048576;                 // [16][1024][64]
    __bf16* VTB = KB + 1048576;                  // [16][64][1024]
    __bf16* WB_e1   = bfw + 31326208;            // 16 * 1024*512
    __bf16* WB_e2   = bfw + 39714816;            // 16 * 512*1024
    // bf16 activation shadows
    __bf16* X0B   = bfw + 48103424;              // [N,512]
    __bf16* X1B   = X0B + 1048576;               // [N,512]
    __bf16* XCATB = X1B + 1048576;               // [N,1024]
    __bf16* OUTSB = XCATB + 2097152;             // [N,1024]
    __bf16* XNB   = OUTSB + 2097152;             // [N,512]
    __bf16* XQB   = XNB + 1048576;               // [N,512]
    __bf16* Q1BB  = XQB + 1048576;               // [N,2048]
    __bf16* ENB   = Q1BB + 4194304;              // [N,256]

    auto wtransN = [&](const float* W, __bf16* Wt, int K, int N, int cnt, long sW, long sD) {
        wtrans_k<<<dim3(N / 64, K / 64, cnt), 256, 0, stream>>>(W, Wt, K, N, sW, sD);
    };
    auto gemm = [&](const __bf16* A, int lda, const __bf16* Bm, float* C_, int ldc,
                    __bf16* Cb, int ldcb, const float* bias, const float* res, int ldres,
                    float alpha, int Nn, int K, int act) {
        gemm_bf16<<<(Nn / 128) * 16, 256, 0, stream>>>(
            A, lda, Bm, C_, ldc, Cb, ldcb, bias, res, ldres, alpha, K, act);
    };

    // ---- weight conversion (same work every call; graph-safe) ----
    wtransN(mp_w, WB_mp, 1024, 512, 1, 0, 0);
    wtransN(qkv_w, WB_qkv, 512, 1536, 4, 512 * 1536, 1536 * 512);
    wtransN(mg_w, WB_mg, 1024, 512, 2, 1024 * 512, 512 * 1024);
    wtransN(q1w, WB_q1, 512, 2048, 2, 512 * 2048, 2048 * 512);
    wtransN(errw, WB_err, 512, 512, 2, 512 * 512, 512 * 512);
    wtransN(ew1, WB_e1, 512, 1024, 16, 524288, 524288);
    wtransN(ew2, WB_e2, 1024, 512, 16, 524288, 524288);
    wtransN(ag1w, WB_ag1, 1024, 2048, 1, 0, 0);
    wtransN(ag2w, WB_ag2, 2048, 512, 1, 0, 0);
    wtransN(head_w, WB_head, 512, VDIM, 1, 0, 0);
    wtransN(mem, WB_memt, 256, 512, 1, 0, 0);                // mem^T [512,256]
    cvta_k<<<256, 256, 0, stream>>>(mem, 512, 512, WB_memn); // mem [256,512] as [N,K]

    // ---- embedding + memory bank ----
    embed_k<<<NTOK, 256, 0, stream>>>(ids, embed_w, X0, X0B);
    gemm(X0B, 512, WB_memn, EN, 256, nullptr, 0, nullptr, nullptr, 0, 1.f, 256, 512, 0);
    smrows_k<<<NTOK, 256, 0, stream>>>(EN, ENB);
    gemm(ENB, 256, WB_memt, RET, 512, nullptr, 0, nullptr, nullptr, 0, 1.f, 512, 256, 0);
    concat_bf_k<<<4096, 256, 0, stream>>>(X0, RET, XCATB);
    gemm(XCATB, 1024, WB_mp, X0, 512, X0B, 512, mp_b, nullptr, 0, 1.f, 512, 1024, 0);

    float* xcur = X0;
    float* xalt = X1;
    __bf16* xcurB = X0B;
    __bf16* xaltB = X1B;
    for (int l = 0; l < 2; ++l) {
        for (int p = 0; p < 2; ++p) {
            const int lp = l * 2 + p;
            const float* hptr = (p == 0) ? xcur : OUTS;
            const __bf16* hptrB = (p == 0) ? xcurB : OUTSB;
            const int hlda = (p == 0) ? 512 : 1024;
            gemm(hptrB, hlda, WB_qkv + (long)lp * 1536 * 512, QKV, 1536, nullptr, 0,
                 qkv_b + (long)lp * 1536, nullptr, 0, 1.f, 1536, 512, 0);
            meanp_k<<<256, 64, 0, stream>>>(hptr, hlda, PART);
            meanr_k<<<4, 256, 0, stream>>>(PART, HMEAN);
            aware_k<<<1, 64, 0, stream>>>(HMEAN, aw_w, aw_b, lp, AWARE);
            qkvprep_k<<<256, 256, 0, stream>>>(QKV, dscale, lp, AWARE, QKB, KB, VTB);
            attn2_k<<<512, 256, 0, stream>>>(QKB, KB, VTB, PRIORB,
                                             (p == 1) ? 1 : 0, OUTS, OUTSB, p * CDIM);
        }
        gemm(OUTSB, 1024, WB_mg + (long)l * 512 * 1024, Z, 512, nullptr, 0,
             mg_b + (long)l * 512, xcur, 512, 1.f, 512, 1024, 0);
        ln_k<<<NTOK, 256, 0, stream>>>(Z, ln_g + (long)l * 512, ln_b + (long)l * 512, XN, XNB);
        gate_k<<<NTOK, 64, 0, stream>>>(XN, gw, gb, l, WV, EIDX);
        route_k<<<1, 256, 0, stream>>>(EIDX, OFFI, LIST, POSMAP);
        moe_g1_k<<<dim3(8, 40), 256, 0, stream>>>(XNB, WB_e1 + (long)l * 8 * 524288,
                eb1 + (long)l * 8192, OFFI, LIST, EHB);
        moe_g2_k<<<dim3(4, 40), 256, 0, stream>>>(EHB, WB_e2 + (long)l * 8 * 524288,
                eb2 + (long)l * 4096, OFFI, EYS);
        reason2_k<<<4096, 256, 0, stream>>>(XN, EYS, WV, POSMAP, REASON);
        gemm(xcurB, 512, WB_q1 + (long)l * 2048 * 512, nullptr, 0, Q1BB, 2048,
             q1b + (long)l * 2048, nullptr, 0, 1.f, 2048, 512, 1);
        qual_k<<<NTOK, 256, 0, stream>>>(Q1BB, q2w, q2b, l, QUAL);
        xq_k<<<4096, 256, 0, stream>>>(xcur, QUAL, XQB);
        gemm(XQB, 512, WB_err + (long)l * 512 * 512, INTRO, 512, nullptr, 0,
             errb + (long)l * 512, xcur, 512, 0.3f, 512, 512, 0);
        concat_bf_k<<<4096, 256, 0, stream>>>(REASON, INTRO, XCATB);
        gemm(XCATB, 1024, WB_ag1, nullptr, 0, Q1BB, 2048, ag1b, nullptr, 0, 1.f, 2048, 1024, 1);
        gemm(Q1BB, 2048, WB_ag2, GATEB, 512, nullptr, 0, ag2b, nullptr, 0, 1.f, 512, 2048, 2);
        final_k<<<4096, 256, 0, stream>>>(REASON, GATEB, pscale, INTRO, xalt, xaltB);
        float* tmp = xcur; xcur = xalt; xalt = tmp;
        __bf16* tmpb = xcurB; xcurB = xaltB; xaltB = tmpb;
    }
    // ---- head ----
    gemm(xcurB, 512, WB_head, out, VDIM, nullptr, 0, head_b, nullptr, 0, 1.f, VDIM, 512, 0);
}

// Round 4
// 1597.124 us; speedup vs baseline: 2.9695x; 1.0515x over previous
//
#include <hip/hip_runtime.h>

// ConsciousTransformer forward. Round 6: (1) gemm_bf16 epilogue rewritten to
// stage C through LDS and emit float4 row-contiguous stores (head GEMM was
// write-bound at 1.5 TB/s from 64B-sector scalar stores). (2) gemm64_bf16
// (64x64 tile) for N<=512 GEMMs which were grid-starved (64 blocks / 256 CUs).
// Dims: C=512, V=32000, L=2, P=2, E=8, HM=1024, H=8, M=256, B=2, T=1024, N=B*T=2048

#define NTOK 2048
#define CDIM 512
#define TLEN 1024
#define NB 2
#define NH 8
#define VDIM 32000

typedef __attribute__((ext_vector_type(4))) float f32x4;
typedef __attribute__((ext_vector_type(8))) __bf16 bf16x8;
typedef __attribute__((ext_vector_type(4))) __bf16 bf16x4;

#define AS1 __attribute__((address_space(1)))
#define AS3 __attribute__((address_space(3)))

__device__ __forceinline__ void g2lds16(const void* g, void* l) {
    __builtin_amdgcn_global_load_lds((const AS1 void*)g, (AS3 void*)l, 16, 0, 0);
}

// ---------------- bf16 MFMA GEMM: C = res + alpha*act(A@B^T + bias) ----------------
// A [M,lda] bf16 (first K cols), B [N,K] bf16 packed, C_ [M,N] fp32 (opt),
// Cb [M,N] bf16 (opt). act: 0=none, 1=silu, 2=tanh. M=2048 fixed (16 m-blocks),
// N mult of 128; K mult of 32. 1-D grid = 16*(N/128), m-fastest within XCD chunk.
// Epilogue stages C tile through LDS for float4 coalesced global stores.
__global__ __launch_bounds__(256) void gemm_bf16(
    const __bf16* __restrict__ A, int lda,
    const __bf16* __restrict__ B,
    float* __restrict__ C_, int ldc,
    __bf16* __restrict__ Cb, int ldcb,
    const float* __restrict__ bias,
    const float* __restrict__ res, int ldres, float alpha,
    int K, int act)
{
    __shared__ __align__(16) char smem[16384];
    __bf16* As = (__bf16*)smem;
    __bf16* Bs = (__bf16*)(smem + 8192);
    float* cs = (float*)smem;          // epilogue reuse: 32 rows x 128 cols f32
    const int tid = threadIdx.x;
    const int w = tid >> 6, lane = tid & 63;
    // bijective XCD swizzle (m204) then m-fastest decomposition
    const int nwg = gridDim.x;
    const int q = nwg >> 3, r = nwg & 7;
    const int xcd = blockIdx.x & 7, ii = blockIdx.x >> 3;
    const int swz = (xcd < r) ? xcd * (q + 1) + ii : r * (q + 1) + (xcd - r) * q + ii;
    const int m0 = (swz & 15) * 128, n0 = (swz >> 4) * 128;
    const int wr = (w >> 1) * 64, wc = (w & 1) * 64;
    f32x4 acc[4][4] = {};
    const int mrow = lane & 15, kq = (lane >> 4) * 8;
    for (int k0 = 0; k0 < K; k0 += 32) {
#pragma unroll
        for (int i = 0; i < 2; ++i) {
            const int boff = w * 2048 + i * 1024 + lane * 16; // byte off in 128x32 bf16 tile
            const int row = boff >> 6;        // 64 B per row
            const int ke = (boff & 63) >> 1;  // bf16 elem within row
            g2lds16(A + (long)(m0 + row) * lda + k0 + ke, (char*)As + (boff - lane * 16));
            g2lds16(B + (long)(n0 + row) * K + k0 + ke, (char*)Bs + (boff - lane * 16));
        }
        __syncthreads();
        bf16x8 af[4], bfr[4];
#pragma unroll
        for (int i = 0; i < 4; ++i)
            af[i] = *(const bf16x8*)(As + (wr + i * 16 + mrow) * 32 + kq);
#pragma unroll
        for (int j = 0; j < 4; ++j)
            bfr[j] = *(const bf16x8*)(Bs + (wc + j * 16 + mrow) * 32 + kq);
#pragma unroll
        for (int i = 0; i < 4; ++i)
#pragma unroll
            for (int j = 0; j < 4; ++j)
                acc[i][j] = __builtin_amdgcn_mfma_f32_16x16x32_bf16(af[i], bfr[j], acc[i][j], 0, 0, 0);
        __syncthreads();
    }
    // ---- epilogue: 4 passes of 32 rows via LDS, coalesced float4 out ----
    const int col_l = lane & 15, row_l = (lane >> 4) * 4;
#pragma unroll
    for (int p = 0; p < 4; ++p) {
        if ((w >> 1) == (p >> 1)) {
#pragma unroll
            for (int iq = 0; iq < 2; ++iq) {
                const int i = (p & 1) * 2 + iq;
#pragma unroll
                for (int j = 0; j < 4; ++j) {
                    const int n_l = wc + j * 16 + col_l;
                    const float bv = bias ? bias[n0 + n_l] : 0.f;
#pragma unroll
                    for (int r2 = 0; r2 < 4; ++r2) {
                        const int lr = iq * 16 + row_l + r2;
                        float v = acc[i][j][r2] + bv;
                        if (act == 1) v = v / (1.f + __expf(-v));
                        else if (act == 2) v = tanhf(v);
                        v *= alpha;
                        cs[lr * 128 + (n_l ^ (((lr >> 2) & 3) << 4))] = v;
                    }
                }
            }
        }
        __syncthreads();
#pragma unroll
        for (int it = 0; it < 4; ++it) {
            const int idx = it * 256 + tid;
            const int row = idx >> 5, c4f = (idx & 31) << 2;
            const int m = m0 + p * 32 + row;
            const int n = n0 + c4f;
            float4 v = *(const float4*)&cs[row * 128 + (c4f ^ (((row >> 2) & 3) << 4))];
            if (res) {
                const float4 rv = *(const float4*)(res + (long)m * ldres + n);
                v.x += rv.x; v.y += rv.y; v.z += rv.z; v.w += rv.w;
            }
            if (C_) *(float4*)(C_ + (long)m * ldc + n) = v;
            if (Cb) {
                bf16x4 b4;
                b4[0] = (__bf16)v.x; b4[1] = (__bf16)v.y;
                b4[2] = (__bf16)v.z; b4[3] = (__bf16)v.w;
                *(bf16x4*)(Cb + (long)m * ldcb + n) = b4;
            }
        }
        __syncthreads();
    }
}

// ---------------- 64x64-tile variant for small-N GEMMs (grid starvation fix) ----------------
__global__ __launch_bounds__(256) void gemm64_bf16(
    const __bf16* __restrict__ A, int lda,
    const __bf16* __restrict__ B,
    float* __restrict__ C_, int ldc,
    __bf16* __restrict__ Cb, int ldcb,
    const float* __restrict__ bias,
    const float* __restrict__ res, int ldres, float alpha,
    int K, int act)
{
    __shared__ __align__(16) char smem[8192];
    __bf16* As = (__bf16*)smem;
    __bf16* Bs = (__bf16*)(smem + 4096);
    float* cs = (float*)smem;          // 32 rows x 64 cols f32
    const int tid = threadIdx.x;
    const int w = tid >> 6, lane = tid & 63;
    const int nwg = gridDim.x;
    const int q = nwg >> 3, r = nwg & 7;
    const int xcd = blockIdx.x & 7, ii = blockIdx.x >> 3;
    const int swz = (xcd < r) ? xcd * (q + 1) + ii : r * (q + 1) + (xcd - r) * q + ii;
    const int m0 = (swz & 31) * 64, n0 = (swz >> 5) * 64;
    const int wr = (w >> 1) * 32, wc = (w & 1) * 32;
    f32x4 acc[2][2] = {};
    const int mrow = lane & 15, kq = (lane >> 4) * 8;
    const int arow = tid >> 2, ke = (tid & 3) * 8;
    for (int k0 = 0; k0 < K; k0 += 32) {
        g2lds16(A + (long)(m0 + arow) * lda + k0 + ke, (char*)As + tid * 16 - lane * 16);
        g2lds16(B + (long)(n0 + arow) * K + k0 + ke, (char*)Bs + tid * 16 - lane * 16);
        __syncthreads();
        bf16x8 af[2], bfr[2];
#pragma unroll
        for (int i = 0; i < 2; ++i)
            af[i] = *(const bf16x8*)(As + (wr + i * 16 + mrow) * 32 + kq);
#pragma unroll
        for (int j = 0; j < 2; ++j)
            bfr[j] = *(const bf16x8*)(Bs + (wc + j * 16 + mrow) * 32 + kq);
#pragma unroll
        for (int i = 0; i < 2; ++i)
#pragma unroll
            for (int j = 0; j < 2; ++j)
                acc[i][j] = __builtin_amdgcn_mfma_f32_16x16x32_bf16(af[i], bfr[j], acc[i][j], 0, 0, 0);
        __syncthreads();
    }
    const int col_l = lane & 15, row_l = (lane >> 4) * 4;
#pragma unroll
    for (int p = 0; p < 2; ++p) {
        if ((w >> 1) == p) {
#pragma unroll
            for (int i = 0; i < 2; ++i)
#pragma unroll
                for (int j = 0; j < 2; ++j) {
                    const int n_l = wc + j * 16 + col_l;
                    const float bv = bias ? bias[n0 + n_l] : 0.f;
#pragma unroll
                    for (int r2 = 0; r2 < 4; ++r2) {
                        const int lr = i * 16 + row_l + r2;
                        float v = acc[i][j][r2] + bv;
                        if (act == 1) v = v / (1.f + __expf(-v));
                        else if (act == 2) v = tanhf(v);
                        v *= alpha;
                        cs[lr * 64 + (n_l ^ (((lr >> 2) & 3) << 4))] = v;
                    }
                }
        }
        __syncthreads();
#pragma unroll
        for (int it = 0; it < 2; ++it) {
            const int idx = it * 256 + tid;
            const int row = idx >> 4, c4f = (idx & 15) << 2;
            const int m = m0 + p * 32 + row;
            const int n = n0 + c4f;
            float4 v = *(const float4*)&cs[row * 64 + (c4f ^ (((row >> 2) & 3) << 4))];
            if (res) {
                const float4 rv = *(const float4*)(res + (long)m * ldres + n);
                v.x += rv.x; v.y += rv.y; v.z += rv.z; v.w += rv.w;
            }
            if (C_) *(float4*)(C_ + (long)m * ldc + n) = v;
            if (Cb) {
                bf16x4 b4;
                b4[0] = (__bf16)v.x; b4[1] = (__bf16)v.y;
                b4[2] = (__bf16)v.z; b4[3] = (__bf16)v.w;
                *(bf16x4*)(Cb + (long)m * ldcb + n) = b4;
            }
        }
        __syncthreads();
    }
}

// ---------------- MoE routing: per-expert 128-aligned segments ----------------
__global__ __launch_bounds__(256) void route_k(const int* __restrict__ eidx,
                                               int* __restrict__ offi,
                                               int* __restrict__ list,
                                               int* __restrict__ posmap)
{
    __shared__ int cnt[8], fill[8], seg[9];
    const int t = threadIdx.x;
    if (t < 8) cnt[t] = 0;
    __syncthreads();
    for (int i = t; i < NTOK * 2; i += 256) atomicAdd(&cnt[eidx[i]], 1);
    __syncthreads();
    if (t == 0) {
        int run = 0;
        for (int e = 0; e < 8; ++e) {
            seg[e] = run;
            run += (cnt[e] + 127) & ~127;
        }
        seg[8] = run;
    }
    __syncthreads();
    if (t < 8) fill[t] = seg[t];
    if (t < 9) offi[t] = seg[t];
    __syncthreads();
    for (int i = t; i < NTOK * 2; i += 256) {
        const int e = eidx[i];
        const int g = atomicAdd(&fill[e], 1);
        list[g] = i;
        posmap[i] = g;
    }
    __syncthreads();
#pragma unroll
    for (int e = 0; e < 8; ++e)
        for (int g = seg[e] + cnt[e] + t; g < seg[e + 1]; g += 256) list[g] = 0;
}

// ---------------- MoE mlp1: gathered-A GEMM + swiglu, bf16 out ----------------
__global__ __launch_bounds__(256) void moe_g1_k(
    const __bf16* __restrict__ A,
    const __bf16* __restrict__ Bw,
    const float* __restrict__ eb1l,
    const int* __restrict__ offi,
    const int* __restrict__ list,
    __bf16* __restrict__ EHB)
{
    const int m0 = blockIdx.y * 128;
    if (m0 >= offi[8]) return;
    int e = 0;
    while (e < 7 && offi[e + 1] <= m0) ++e;   // segments are 128-aligned
    const __bf16* B = Bw + (long)e * (1024 * 512);
    const float* bias = eb1l + e * 1024;
    __shared__ __bf16 As[128 * 32];
    __shared__ __bf16 Bs[128 * 32];
    __shared__ int toks[128];
    const int tid = threadIdx.x;
    if (tid < 128) toks[tid] = list[m0 + tid] >> 1;
    __syncthreads();
    const int w = tid >> 6, lane = tid & 63;
    const int n0 = blockIdx.x * 128;
    const int wr = (w >> 1) * 64, wc = (w & 1) * 64;
    f32x4 acc[4][4] = {};
    const int mrow = lane & 15, kq = (lane >> 4) * 8;
    for (int k0 = 0; k0 < 512; k0 += 32) {
#pragma unroll
        for (int i = 0; i < 2; ++i) {
            const int boff = w * 2048 + i * 1024 + lane * 16;
            const int row = boff >> 6;
            const int ke = (boff & 63) >> 1;
            g2lds16(A + (long)toks[row] * 512 + k0 + ke, (char*)As + (boff - lane * 16));
            g2lds16(B + (long)(n0 + row) * 512 + k0 + ke, (char*)Bs + (boff - lane * 16));
        }
        __syncthreads();
        bf16x8 af[4], bfr[4];
#pragma unroll
        for (int i = 0; i < 4; ++i)
            af[i] = *(const bf16x8*)(As + (wr + i * 16 + mrow) * 32 + kq);
#pragma unroll
        for (int j = 0; j < 4; ++j)
            bfr[j] = *(const bf16x8*)(Bs + (wc + j * 16 + mrow) * 32 + kq);
#pragma unroll
        for (int i = 0; i < 4; ++i)
#pragma unroll
            for (int j = 0; j < 4; ++j)
                acc[i][j] = __builtin_amdgcn_mfma_f32_16x16x32_bf16(af[i], bfr[j], acc[i][j], 0, 0, 0);
        __syncthreads();
    }
    const int col_l = lane & 15, row_l = (lane >> 4) * 4;
#pragma unroll
    for (int i = 0; i < 4; ++i)
#pragma unroll
        for (int j = 0; j < 4; ++j) {
            const int n = n0 + wc + j * 16 + col_l;
            const float bv = bias[n];
#pragma unroll
            for (int r = 0; r < 4; ++r) {
                const int g = m0 + wr + i * 16 + row_l + r;
                const float v = acc[i][j][r] + bv;
                EHB[(long)g * 1024 + n] = (__bf16)(v * v / (1.f + __expf(-v)));
            }
        }
}

// ---------------- MoE mlp2: segment-contiguous GEMM, f32 out ----------------
__global__ __launch_bounds__(256) void moe_g2_k(
    const __bf16* __restrict__ A,
    const __bf16* __restrict__ Bw,
    const float* __restrict__ eb2l,
    const int* __restrict__ offi,
    float* __restrict__ EYS)
{
    const int m0 = blockIdx.y * 128;
    if (m0 >= offi[8]) return;
    int e = 0;
    while (e < 7 && offi[e + 1] <= m0) ++e;
    const __bf16* B = Bw + (long)e * (512 * 1024);
    const float* bias = eb2l + e * 512;
    __shared__ __bf16 As[128 * 32];
    __shared__ __bf16 Bs[128 * 32];
    const int tid = threadIdx.x;
    const int w = tid >> 6, lane = tid & 63;
    const int n0 = blockIdx.x * 128;
    const int wr = (w >> 1) * 64, wc = (w & 1) * 64;
    f32x4 acc[4][4] = {};
    const int mrow = lane & 15, kq = (lane >> 4) * 8;
    for (int k0 = 0; k0 < 1024; k0 += 32) {
#pragma unroll
        for (int i = 0; i < 2; ++i) {
            const int boff = w * 2048 + i * 1024 + lane * 16;
            const int row = boff >> 6;
            const int ke = (boff & 63) >> 1;
            g2lds16(A + (long)(m0 + row) * 1024 + k0 + ke, (char*)As + (boff - lane * 16));
            g2lds16(B + (long)(n0 + row) * 1024 + k0 + ke, (char*)Bs + (boff - lane * 16));
        }
        __syncthreads();
        bf16x8 af[4], bfr[4];
#pragma unroll
        for (int i = 0; i < 4; ++i)
            af[i] = *(const bf16x8*)(As + (wr + i * 16 + mrow) * 32 + kq);
#pragma unroll
        for (int j = 0; j < 4; ++j)
            bfr[j] = *(const bf16x8*)(Bs + (wc + j * 16 + mrow) * 32 + kq);
#pragma unroll
        for (int i = 0; i < 4; ++i)
#pragma unroll
            for (int j = 0; j < 4; ++j)
                acc[i][j] = __builtin_amdgcn_mfma_f32_16x16x32_bf16(af[i], bfr[j], acc[i][j], 0, 0, 0);
        __syncthreads();
    }
    const int col_l = lane & 15, row_l = (lane >> 4) * 4;
#pragma unroll
    for (int i = 0; i < 4; ++i)
#pragma unroll
        for (int j = 0; j < 4; ++j) {
            const int n = n0 + wc + j * 16 + col_l;
            const float bv = bias[n];
#pragma unroll
            for (int r = 0; r < 4; ++r) {
                const int g = m0 + wr + i * 16 + row_l + r;
                EYS[(long)g * 512 + n] = acc[i][j][r] + bv;
            }
        }
}

// ---------------- reason = xn + 0.5*(w0*ey[pos0] + w1*ey[pos1]) ----------------
__global__ __launch_bounds__(256) void reason2_k(const float* __restrict__ xn,
                                                 const float* __restrict__ EYS,
                                                 const float* __restrict__ wv,
                                                 const int* __restrict__ posmap,
                                                 float* __restrict__ reason)
{
    const long i = (long)blockIdx.x * 256 + threadIdx.x;
    const long n = i >> 9;
    const int c = (int)(i & 511);
    const int g0 = posmap[n * 2], g1 = posmap[n * 2 + 1];
    const float v = wv[n * 2] * EYS[(long)g0 * 512 + c] + wv[n * 2 + 1] * EYS[(long)g1 * 512 + c];
    reason[i] = xn[i] + 0.5f * v;
}

// ---------------- weight transpose+convert (batched): W [K,N] f32 -> Wt [N,K] bf16 ----------------
__global__ __launch_bounds__(256) void wtrans_k(const float* __restrict__ W0,
                                                __bf16* __restrict__ Wt0, int K, int N,
                                                long sW, long sD)
{
    const float* W = W0 + (long)blockIdx.z * sW;
    __bf16* Wt = Wt0 + (long)blockIdx.z * sD;
    __shared__ float tile[64][65];
    const int k0 = blockIdx.y * 64, n0 = blockIdx.x * 64;
    const int t = threadIdx.x;
#pragma unroll
    for (int i = 0; i < 4; ++i) {
        const int r = (t >> 4) + i * 16;
        const int c = (t & 15) * 4;
        float4 v = *(const float4*)(W + (long)(k0 + r) * N + n0 + c);
        tile[r][c] = v.x; tile[r][c + 1] = v.y; tile[r][c + 2] = v.z; tile[r][c + 3] = v.w;
    }
    __syncthreads();
#pragma unroll
    for (int i = 0; i < 4; ++i) {
        const int rr = (t >> 4) + i * 16;   // n
        const int cc = (t & 15) * 4;        // k
        __bf16* o = Wt + (long)(n0 + rr) * K + k0 + cc;
        o[0] = (__bf16)tile[cc][rr];
        o[1] = (__bf16)tile[cc + 1][rr];
        o[2] = (__bf16)tile[cc + 2][rr];
        o[3] = (__bf16)tile[cc + 3][rr];
    }
}

// ---------------- f32 -> bf16 convert (one-time, mem) ----------------
__global__ __launch_bounds__(256) void cvta_k(const float* __restrict__ src, int lda, int K,
                                              __bf16* __restrict__ dst)
{
    const int row = blockIdx.x, t = threadIdx.x;
    const float* s = src + (long)row * lda;
    __bf16* d = dst + (long)row * K;
    for (int c = t * 4; c < K; c += 1024) {
        float4 v = *(const float4*)(s + c);
        d[c] = (__bf16)v.x; d[c + 1] = (__bf16)v.y; d[c + 2] = (__bf16)v.z; d[c + 3] = (__bf16)v.w;
    }
}

// ---------------- embedding gather (f32 + bf16 shadow) ----------------
__global__ __launch_bounds__(256) void embed_k(const int* __restrict__ ids,
                                               const float* __restrict__ ew,
                                               float* __restrict__ x,
                                               __bf16* __restrict__ xb)
{
    const int n = blockIdx.x, t = threadIdx.x;
    const long r = (long)ids[n] * CDIM;
    const float v0 = ew[r + t], v1 = ew[r + 256 + t];
    x[(long)n * CDIM + t]       = v0;
    x[(long)n * CDIM + 256 + t] = v1;
    xb[(long)n * CDIM + t]       = (__bf16)v0;
    xb[(long)n * CDIM + 256 + t] = (__bf16)v1;
}

// ---------------- row softmax (width 256) -> bf16 out ----------------
__global__ __launch_bounds__(256) void smrows_k(const float* __restrict__ a,
                                                __bf16* __restrict__ ob)
{
    const int n = blockIdx.x, t = threadIdx.x;
    __shared__ float rs[256];
    float v = a[(long)n * 256 + t];
    rs[t] = v; __syncthreads();
    for (int o = 128; o; o >>= 1) { if (t < o) rs[t] = fmaxf(rs[t], rs[t + o]); __syncthreads(); }
    const float m = rs[0]; __syncthreads();
    const float e = __expf(v - m);
    rs[t] = e; __syncthreads();
    for (int o = 128; o; o >>= 1) { if (t < o) rs[t] += rs[t + o]; __syncthreads(); }
    ob[(long)n * 256 + t] = (__bf16)(e / rs[0]);
}

// ---------------- concat two f32 [N,C] -> bf16 [N,2C] ----------------
__global__ __launch_bounds__(256) void concat_bf_k(const float* __restrict__ a,
                                                   const float* __restrict__ b,
                                                   __bf16* __restrict__ o)
{
    const long i = (long)blockIdx.x * 256 + threadIdx.x;
    const long n = i >> 9;
    const int c = (int)(i & 511);
    o[n * 1024 + c]       = (__bf16)a[i];
    o[n * 1024 + 512 + c] = (__bf16)b[i];
}

// ---------------- mean over T (partial + reduce) ----------------
__global__ __launch_bounds__(64) void meanp_k(const float* __restrict__ A, int lda,
                                              float* __restrict__ part)
{
    const int bid = blockIdx.x;
    const int ts = bid & 15;
    const int cg = (bid >> 4) & 7;
    const int b  = bid >> 7;
    const int c  = cg * 64 + threadIdx.x;
    const float* p = A + ((long)b * TLEN + ts * 64) * lda + c;
    float s = 0.f;
    for (int t = 0; t < 64; ++t) s += p[(long)t * lda];
    part[(long)ts * 1024 + b * 512 + c] = s;
}
__global__ __launch_bounds__(256) void meanr_k(const float* __restrict__ part,
                                               float* __restrict__ hm)
{
    const int i = blockIdx.x * 256 + threadIdx.x;
    float s = 0.f;
    for (int ts = 0; ts < 16; ++ts) s += part[ts * 1024 + i];
    hm[i] = s * (1.f / 1024.f);
}

// ---------------- awareness ----------------
__global__ __launch_bounds__(64) void aware_k(const float* __restrict__ hm,
                                              const float* __restrict__ aw_w,
                                              const float* __restrict__ aw_b,
                                              int lp, float* __restrict__ out)
{
    const int t = threadIdx.x;
    if (t < NB * NH) {
        const int b = t >> 3, hh = t & 7;
        const float* W = aw_w + (long)lp * CDIM * NH;
        const float* x = hm + b * CDIM;
        float s = aw_b[lp * NH + hh];
        for (int c = 0; c < CDIM; ++c) s += x[c] * W[c * NH + hh];
        out[t] = s;
    }
}

// ---------------- per-phase attention prep: fp32 QKV -> bf16 Q*scale, K, V^T ----------------
__global__ __launch_bounds__(256) void qkvprep_k(
    const float* __restrict__ qkv,
    const float* __restrict__ dscale, int lp,
    const float* __restrict__ aware,
    __bf16* __restrict__ QKB, __bf16* __restrict__ KB, __bf16* __restrict__ VTB)
{
    const int bh = blockIdx.x >> 4;
    const int tc = blockIdx.x & 15;
    const int b = bh >> 3, h = bh & 7;
    const int tid = threadIdx.x;
    const float sc = dscale[lp] * aware[bh];
    __shared__ float vt[64][68];
    const int row = tid >> 2, c0 = (tid & 3) * 16;
    const long rbase = ((long)(b * 1024 + tc * 64 + row)) * 1536 + h * 64 + c0;
    {
        bf16x8 qo[2], ko[2];
#pragma unroll
        for (int i = 0; i < 2; ++i)
#pragma unroll
            for (int jj = 0; jj < 2; ++jj) {
                const float4 qq = *(const float4*)(qkv + rbase + (i * 2 + jj) * 4);
                const float4 kk = *(const float4*)(qkv + rbase + 512 + (i * 2 + jj) * 4);
                qo[i][jj * 4 + 0] = (__bf16)(qq.x * sc);
                qo[i][jj * 4 + 1] = (__bf16)(qq.y * sc);
                qo[i][jj * 4 + 2] = (__bf16)(qq.z * sc);
                qo[i][jj * 4 + 3] = (__bf16)(qq.w * sc);
                ko[i][jj * 4 + 0] = (__bf16)kk.x;
                ko[i][jj * 4 + 1] = (__bf16)kk.y;
                ko[i][jj * 4 + 2] = (__bf16)kk.z;
                ko[i][jj * 4 + 3] = (__bf16)kk.w;
            }
        const long obase = (long)bh * 65536 + (long)(tc * 64 + row) * 64 + c0;
        *(bf16x8*)(QKB + obase) = qo[0];
        *(bf16x8*)(QKB + obase + 8) = qo[1];
        *(bf16x8*)(KB + obase) = ko[0];
        *(bf16x8*)(KB + obase + 8) = ko[1];
    }
    {
        const long vbase = ((long)(b * 1024 + tc * 64 + row)) * 1536 + 1024 + h * 64 + c0;
#pragma unroll
        for (int i = 0; i < 4; ++i) {
            const float4 v = *(const float4*)(qkv + vbase + i * 4);
            vt[row][c0 + i * 4 + 0] = v.x;
            vt[row][c0 + i * 4 + 1] = v.y;
            vt[row][c0 + i * 4 + 2] = v.z;
            vt[row][c0 + i * 4 + 3] = v.w;
        }
    }
    __syncthreads();
    {
        const int d = row;                 // 0..63
        const int s0 = c0;                 // 0,16,32,48
        bf16x8 o0, o1;
#pragma unroll
        for (int j = 0; j < 8; ++j) o0[j] = (__bf16)vt[s0 + j][d];
#pragma unroll
        for (int j = 0; j < 8; ++j) o1[j] = (__bf16)vt[s0 + 8 + j][d];
        __bf16* dst = VTB + (long)bh * 65536 + (long)d * 1024 + tc * 64 + s0;
        *(bf16x8*)dst = o0;
        *(bf16x8*)(dst + 8) = o1;
    }
}

// ---------------- MFMA attention: 32 Q-rows per block, full-row softmax + prior ----------------
#define RB 32
__global__ __launch_bounds__(256) void attn2_k(
    const __bf16* __restrict__ QKB,
    const __bf16* __restrict__ KB,
    const __bf16* __restrict__ VTB,
    __bf16* __restrict__ prior,
    int use_prior,
    float* __restrict__ outs, __bf16* __restrict__ outsb, int out_off)
{
    __shared__ __align__(16) __bf16 qs[RB * 64];
    __shared__ __align__(16) __bf16 kv[2][128 * 64];
    __shared__ __align__(16) __bf16 ss[RB * 1024];
    const int tid = threadIdx.x;
    const int w = tid >> 6, lane = tid & 63;
    const int rb = blockIdx.x & 31;
    const int bh = blockIdx.x >> 5;
    const int b = bh >> 3, h = bh & 7;
    const int t0 = rb * RB;
    const long qkbase = (long)bh * 65536;
    const int mrow = lane & 15, kq = (lane >> 4) * 8;

    {
        const int row = tid >> 3, gl = tid & 7;
        const int gs = gl ^ (row & 7);
        g2lds16(QKB + qkbase + (long)(t0 + row) * 64 + gs * 8,
                (char*)qs + tid * 16 - lane * 16);
    }
    {
        for (int it = 0; it < 4; ++it) {
            const int idx = it * 256 + tid;
            const int row = idx >> 3, gl = idx & 7;
            const int gs = gl ^ (row & 7);
            g2lds16(KB + qkbase + (long)row * 64 + gs * 8,
                    (char*)kv[0] + idx * 16 - lane * 16);
        }
        __syncthreads();
        int buf = 0;
        const int ntb = w * 2;
        for (int c = 0; c < 8; ++c) {
            if (c < 7) {
                const int s0n = (c + 1) * 128;
                for (int it = 0; it < 4; ++it) {
                    const int idx = it * 256 + tid;
                    const int row = idx >> 3, gl = idx & 7;
                    const int gs = gl ^ (row & 7);
                    g2lds16(KB + qkbase + (long)(s0n + row) * 64 + gs * 8,
                            (char*)kv[buf ^ 1] + idx * 16 - lane * 16);
                }
            }
            f32x4 accs[2][2] = {};
#pragma unroll
            for (int k0 = 0; k0 < 64; k0 += 32) {
                bf16x8 aq[2], bk[2];
#pragma unroll
                for (int mt = 0; mt < 2; ++mt) {
                    const int r = mt * 16 + mrow;
                    const int col = k0 + kq;
                    aq[mt] = *(const bf16x8*)(qs + r * 64 + (((col >> 3) ^ (r & 7)) << 3));
                }
#pragma unroll
                for (int j = 0; j < 2; ++j) {
                    const int nl = (ntb + j) * 16 + mrow;
                    const int col = k0 + kq;
                    bk[j] = *(const bf16x8*)(kv[buf] + nl * 64 + (((col >> 3) ^ (nl & 7)) << 3));
                }
#pragma unroll
                for (int mt = 0; mt < 2; ++mt)
#pragma unroll
                    for (int j = 0; j < 2; ++j)
                        accs[mt][j] = __builtin_amdgcn_mfma_f32_16x16x32_bf16(aq[mt], bk[j], accs[mt][j], 0, 0, 0);
            }
            const int col_l = lane & 15, row_l = (lane >> 4) * 4;
#pragma unroll
            for (int mt = 0; mt < 2; ++mt)
#pragma unroll
                for (int j = 0; j < 2; ++j) {
                    const int ccol = c * 128 + (ntb + j) * 16 + col_l;
#pragma unroll
                    for (int r = 0; r < 4; ++r) {
                        const int rr = mt * 16 + row_l + r;
                        ss[rr * 1024 + (((ccol >> 3) ^ (rr & 7)) << 3) + (ccol & 7)] = (__bf16)accs[mt][j][r];
                    }
                }
            __syncthreads();
            buf ^= 1;
        }
    }
    for (int it = 0; it < 4; ++it) {
        const int idx = it * 256 + tid;
        const int d = idx >> 4, gl = idx & 15;
        const int gs = gl ^ (d & 7);
        g2lds16(VTB + (long)bh * 65536 + (long)d * 1024 + gs * 8,
                (char*)kv[0] + idx * 16 - lane * 16);
    }
    {
        const int r = tid >> 3;
        const int li = tid & 7;
        const int rsw = r & 7;
        float mx = -1e30f;
        for (int j = 0; j < 16; ++j) {
            const int c = j * 64 + li * 8;
            bf16x8 v = *(const bf16x8*)(ss + r * 1024 + (((c >> 3) ^ rsw) << 3));
#pragma unroll
            for (int q = 0; q < 8; ++q) mx = fmaxf(mx, (float)v[q]);
        }
        mx = fmaxf(mx, __shfl_xor(mx, 1));
        mx = fmaxf(mx, __shfl_xor(mx, 2));
        mx = fmaxf(mx, __shfl_xor(mx, 4));
        float sum = 0.f;
        for (int j = 0; j < 16; ++j) {
            const int c = j * 64 + li * 8;
            __bf16* p = ss + r * 1024 + (((c >> 3) ^ rsw) << 3);
            bf16x8 v = *(const bf16x8*)p;
            bf16x8 e;
#pragma unroll
            for (int q = 0; q < 8; ++q) {
                const float ev = __expf((float)v[q] - mx);
                sum += ev;
                e[q] = (__bf16)ev;
            }
            *(bf16x8*)p = e;
        }
        sum += __shfl_xor(sum, 1);
        sum += __shfl_xor(sum, 2);
        sum += __shfl_xor(sum, 4);
        const float rinv = 1.f / sum;
        const long pbase = ((long)bh * 1024 + t0 + r) * 1024;
        for (int j = 0; j < 16; ++j) {
            const int c = j * 64 + li * 8;
            __bf16* p = ss + r * 1024 + (((c >> 3) ^ rsw) << 3);
            bf16x8 v = *(const bf16x8*)p;
            bf16x8 o;
            if (use_prior) {
                bf16x8 pr = *(const bf16x8*)(prior + pbase + c);
#pragma unroll
                for (int q = 0; q < 8; ++q)
                    o[q] = (__bf16)((float)v[q] * rinv + 0.3f * (float)pr[q]);
            } else {
#pragma unroll
                for (int q = 0; q < 8; ++q)
                    o[q] = (__bf16)((float)v[q] * rinv);
            }
            *(bf16x8*)p = o;
            *(bf16x8*)(prior + pbase + c) = o;
        }
    }
    __syncthreads();
    {
        f32x4 po[2] = {};
        int buf = 0;
        const int mt = w >> 1;
        const int ntb2 = (w & 1) * 2;
        for (int c = 0; c < 8; ++c) {
            if (c < 7) {
                const int s0n = (c + 1) * 128;
                for (int it = 0; it < 4; ++it) {
                    const int idx = it * 256 + tid;
                    const int d = idx >> 4, gl = idx & 15;
                    const int gs = gl ^ (d & 7);
                    g2lds16(VTB + (long)bh * 65536 + (long)d * 1024 + s0n + gs * 8,
                            (char*)kv[buf ^ 1] + idx * 16 - lane * 16);
                }
            }
#pragma unroll
            for (int ks = 0; ks < 4; ++ks) {
                const int r = mt * 16 + mrow;
                const int cola = c * 128 + ks * 32 + kq;
                bf16x8 pa = *(const bf16x8*)(ss + r * 1024 + (((cola >> 3) ^ (r & 7)) << 3));
                bf16x8 vb[2];
#pragma unroll
                for (int j = 0; j < 2; ++j) {
                    const int d = (ntb2 + j) * 16 + mrow;
                    const int colv = ks * 32 + kq;
                    vb[j] = *(const bf16x8*)(kv[buf] + d * 128 + (((colv >> 3) ^ (d & 7)) << 3));
                }
                po[0] = __builtin_amdgcn_mfma_f32_16x16x32_bf16(pa, vb[0], po[0], 0, 0, 0);
                po[1] = __builtin_amdgcn_mfma_f32_16x16x32_bf16(pa, vb[1], po[1], 0, 0, 0);
            }
            __syncthreads();
            buf ^= 1;
        }
        const int col_l = lane & 15, row_l = (lane >> 4) * 4;
#pragma unroll
        for (int j = 0; j < 2; ++j) {
            const int d = out_off + h * 64 + (ntb2 + j) * 16 + col_l;
#pragma unroll
            for (int r = 0; r < 4; ++r) {
                const int trow = t0 + mt * 16 + row_l + r;
                float v = po[j][r];
                v = v / (1.f + __expf(-v));
                const long oi = ((long)(b * 1024 + trow)) * 1024 + d;
                outs[oi] = v;
                outsb[oi] = (__bf16)v;
            }
        }
    }
}

// ---------------- layernorm over C=512 (f32 + bf16 shadow) ----------------
__global__ __launch_bounds__(256) void ln_k(const float* __restrict__ z,
                                            const float* __restrict__ g,
                                            const float* __restrict__ bb,
                                            float* __restrict__ xn,
                                            __bf16* __restrict__ xnb)
{
    const int n = blockIdx.x, t = threadIdx.x;
    __shared__ float rs[256], rq[256];
    const float v0 = z[(long)n * 512 + t];
    const float v1 = z[(long)n * 512 + 256 + t];
    rs[t] = v0 + v1;
    rq[t] = v0 * v0 + v1 * v1;
    __syncthreads();
    for (int o = 128; o; o >>= 1) {
        if (t < o) { rs[t] += rs[t + o]; rq[t] += rq[t + o]; }
        __syncthreads();
    }
    const float mu = rs[0] * (1.f / 512.f);
    const float var = rq[0] * (1.f / 512.f) - mu * mu;
    const float rstd = rsqrtf(var + 1e-5f);
    const float o0 = (v0 - mu) * rstd * g[t] + bb[t];
    const float o1 = (v1 - mu) * rstd * g[t + 256] + bb[t + 256];
    xn[(long)n * 512 + t]       = o0;
    xn[(long)n * 512 + 256 + t] = o1;
    xnb[(long)n * 512 + t]       = (__bf16)o0;
    xnb[(long)n * 512 + 256 + t] = (__bf16)o1;
}

// ---------------- MoE gate ----------------
__global__ __launch_bounds__(64) void gate_k(const float* __restrict__ xn,
                                             const float* __restrict__ gw,
                                             const float* __restrict__ gb,
                                             int l, float* __restrict__ wv,
                                             int* __restrict__ eidx)
{
    const int n = blockIdx.x, t = threadIdx.x;
    const int e = t & 7, ch = t >> 3;
    const float* W = gw + (long)l * CDIM * 8;
    float part = 0.f;
    for (int k = ch * 64; k < ch * 64 + 64; ++k) part += xn[(long)n * CDIM + k] * W[k * 8 + e];
    part += __shfl_xor(part, 8, 64);
    part += __shfl_xor(part, 16, 64);
    part += __shfl_xor(part, 32, 64);
    __shared__ float lg[8];
    if (t < 8) lg[t] = part + gb[l * 8 + t];
    __syncthreads();
    if (t == 0) {
        float m = lg[0];
        for (int i = 1; i < 8; ++i) m = fmaxf(m, lg[i]);
        float p[8], s = 0.f;
        for (int i = 0; i < 8; ++i) { p[i] = __expf(lg[i] - m); s += p[i]; }
        const float inv = 1.f / s;
        int i0 = 0;
        for (int i = 1; i < 8; ++i) if (p[i] > p[i0]) i0 = i;
        int i1 = (i0 == 0) ? 1 : 0;
        for (int i = 0; i < 8; ++i) { if (i == i0) continue; if (p[i] > p[i1]) i1 = i; }
        eidx[n * 2] = i0; eidx[n * 2 + 1] = i1;
        wv[n * 2] = p[i0] * inv; wv[n * 2 + 1] = p[i1] * inv;
    }
}

// ---------------- quality (bf16 input) ----------------
__global__ __launch_bounds__(256) void qual_k(const __bf16* __restrict__ t1,
                                              const float* __restrict__ q2w,
                                              const float* __restrict__ q2b,
                                              int l, float* __restrict__ qual)
{
    const int n = blockIdx.x, t = threadIdx.x;
    const float* W = q2w + (long)l * 2048;
    float s = 0.f;
    for (int k = t; k < 2048; k += 256) s += (float)t1[(long)n * 2048 + k] * W[k];
    __shared__ float rs[256];
    rs[t] = s; __syncthreads();
    for (int o = 128; o; o >>= 1) { if (t < o) rs[t] += rs[t + o]; __syncthreads(); }
    if (t == 0) {
        const float q = rs[0] + q2b[l];
        qual[n] = 1.f / (1.f + __expf(-q));
    }
}

// ---------------- xq = x_in * (1 - quality), bf16 out ----------------
__global__ __launch_bounds__(256) void xq_k(const float* __restrict__ x_in,
                                            const float* __restrict__ qual,
                                            __bf16* __restrict__ xqb)
{
    const long i = (long)blockIdx.x * 256 + threadIdx.x;
    const long n = i >> 9;
    xqb[i] = (__bf16)(x_in[i] * (1.f - qual[n]));
}

// ---------------- x = reason + gate*pscale*intro (f32 + bf16 shadow) ----------------
__global__ __launch_bounds__(256) void final_k(const float* __restrict__ reason,
                                               const float* __restrict__ gate,
                                               const float* __restrict__ pscale,
                                               const float* __restrict__ intro,
                                               float* __restrict__ xo,
                                               __bf16* __restrict__ xob)
{
    const long i = (long)blockIdx.x * 256 + threadIdx.x;
    const int c = (int)(i & 511);
    const float v = reason[i] + gate[i] * pscale[c] * intro[i];
    xo[i] = v;
    xob[i] = (__bf16)v;
}

// =======================================================================
extern "C" void kernel_launch(void* const* d_in, const int* in_sizes, int n_in,
                              void* d_out, int out_size, void* d_ws, size_t ws_size,
                              hipStream_t stream)
{
    (void)in_sizes; (void)n_in; (void)out_size; (void)ws_size;
    const int*   ids     = (const int*)  d_in[0];
    const float* embed_w = (const float*)d_in[1];
    const float* mem     = (const float*)d_in[2];
    const float* mp_w    = (const float*)d_in[3];
    const float* mp_b    = (const float*)d_in[4];
    const float* qkv_w   = (const float*)d_in[5];
    const float* qkv_b   = (const float*)d_in[6];
    const float* aw_w    = (const float*)d_in[7];
    const float* aw_b    = (const float*)d_in[8];
    const float* dscale  = (const float*)d_in[9];
    const float* mg_w    = (const float*)d_in[10];
    const float* mg_b    = (const float*)d_in[11];
    const float* ln_g    = (const float*)d_in[12];
    const float* ln_b    = (const float*)d_in[13];
    const float* gw      = (const float*)d_in[14];
    const float* gb      = (const float*)d_in[15];
    const float* ew1     = (const float*)d_in[16];
    const float* eb1     = (const float*)d_in[17];
    const float* ew2     = (const float*)d_in[18];
    const float* eb2     = (const float*)d_in[19];
    const float* q1w     = (const float*)d_in[20];
    const float* q1b     = (const float*)d_in[21];
    const float* q2w     = (const float*)d_in[22];
    const float* q2b     = (const float*)d_in[23];
    const float* errw    = (const float*)d_in[24];
    const float* errb    = (const float*)d_in[25];
    const float* ag1w    = (const float*)d_in[26];
    const float* ag1b    = (const float*)d_in[27];
    const float* ag2w    = (const float*)d_in[28];
    const float* ag2b    = (const float*)d_in[29];
    const float* pscale  = (const float*)d_in[30];
    const float* head_w  = (const float*)d_in[31];
    const float* head_b  = (const float*)d_in[32];
    float* out = (float*)d_out;
    float* ws  = (float*)d_ws;

    const long NC = (long)NTOK * CDIM; // 1,048,576
    float* X0   = ws;
    float* X1   = ws + NC;
    float* RET  = ws + 2 * NC;
    float* QKV  = ws + 5 * NC;       // [N,3C]
    float* OUTS = ws + 8 * NC;       // [N,2C]
    float* EN   = ws + 10 * NC;      // [N,256]
    float* SM   = ws + 10 * NC + NC / 2;
    float* PART = SM;
    float* HMEAN= SM + 16384;
    float* AWARE= SM + 17408;
    float* QUAL = SM + 17472;
    float* WV   = SM + 19520;
    int*   EIDX = (int*)(SM + 23616);
    int*   OFFI = (int*)(SM + 27712);   // 16 ints
    int*   LIST = (int*)(SM + 27728);   // 5120 ints
    int*   POSMAP = (int*)(SM + 32848); // 4096 ints
    float* R      = ws + 11 * NC;
    __bf16* PRIORB = (__bf16*)R;     // [16][1024][1024] bf16 = 8*NC floats (overlay)
    float* Z      = R;
    float* XN     = R + NC;
    float* REASON = R + 2 * NC;
    float* INTRO  = R + 3 * NC;
    float* GATEB  = R + 5 * NC;
    __bf16* EHB   = (__bf16*)(R + 6 * NC); // [5120,1024] bf16
    float* EYS    = R + 9 * NC;            // [5120,512] f32

    // bf16 region after 27*NC floats
    __bf16* bfw = (__bf16*)(ws + 27 * NC);
    __bf16* WB_mp   = bfw;                       // 512*1024
    __bf16* WB_qkv  = bfw + 524288;              // 4 * 1536*512
    __bf16* WB_mg   = bfw + 3670016;             // 2 * 512*1024
    __bf16* WB_q1   = bfw + 4718592;             // 2 * 2048*512
    __bf16* WB_err  = bfw + 6815744;             // 2 * 512*512
    __bf16* WB_ag1  = bfw + 7340032;             // 2048*1024
    __bf16* WB_ag2  = bfw + 9437184;             // 512*2048
    __bf16* WB_memn = bfw + 10485760;            // 256*512
    __bf16* WB_memt = bfw + 10616832;            // 512*256
    __bf16* WB_head = bfw + 10747904;            // 32000*512
    __bf16* QKB = bfw + 27131904;                // [16][1024][64]
    __bf16* KB  = QKB + 1048576;                 // [16][1024][64]
    __bf16* VTB = KB + 1048576;                  // [16][64][1024]
    __bf16* WB_e1   = bfw + 31326208;            // 16 * 1024*512
    __bf16* WB_e2   = bfw + 39714816;            // 16 * 512*1024
    // bf16 activation shadows
    __bf16* X0B   = bfw + 48103424;              // [N,512]
    __bf16* X1B   = X0B + 1048576;               // [N,512]
    __bf16* XCATB = X1B + 1048576;               // [N,1024]
    __bf16* OUTSB = XCATB + 2097152;             // [N,1024]
    __bf16* XNB   = OUTSB + 2097152;             // [N,512]
    __bf16* XQB   = XNB + 1048576;               // [N,512]
    __bf16* Q1BB  = XQB + 1048576;               // [N,2048]
    __bf16* ENB   = Q1BB + 4194304;              // [N,256]

    auto wtransN = [&](const float* W, __bf16* Wt, int K, int N, int cnt, long sW, long sD) {
        wtrans_k<<<dim3(N / 64, K / 64, cnt), 256, 0, stream>>>(W, Wt, K, N, sW, sD);
    };
    auto gemm = [&](const __bf16* A, int lda, const __bf16* Bm, float* C_, int ldc,
                    __bf16* Cb, int ldcb, const float* bias, const float* res, int ldres,
                    float alpha, int Nn, int K, int act) {
        if (Nn <= 512)
            gemm64_bf16<<<(Nn / 64) * 32, 256, 0, stream>>>(
                A, lda, Bm, C_, ldc, Cb, ldcb, bias, res, ldres, alpha, K, act);
        else
            gemm_bf16<<<(Nn / 128) * 16, 256, 0, stream>>>(
                A, lda, Bm, C_, ldc, Cb, ldcb, bias, res, ldres, alpha, K, act);
    };

    // ---- weight conversion (same work every call; graph-safe) ----
    wtransN(mp_w, WB_mp, 1024, 512, 1, 0, 0);
    wtransN(qkv_w, WB_qkv, 512, 1536, 4, 512 * 1536, 1536 * 512);
    wtransN(mg_w, WB_mg, 1024, 512, 2, 1024 * 512, 512 * 1024);
    wtransN(q1w, WB_q1, 512, 2048, 2, 512 * 2048, 2048 * 512);
    wtransN(errw, WB_err, 512, 512, 2, 512 * 512, 512 * 512);
    wtransN(ew1, WB_e1, 512, 1024, 16, 524288, 524288);
    wtransN(ew2, WB_e2, 1024, 512, 16, 524288, 524288);
    wtransN(ag1w, WB_ag1, 1024, 2048, 1, 0, 0);
    wtransN(ag2w, WB_ag2, 2048, 512, 1, 0, 0);
    wtransN(head_w, WB_head, 512, VDIM, 1, 0, 0);
    wtransN(mem, WB_memt, 256, 512, 1, 0, 0);                // mem^T [512,256]
    cvta_k<<<256, 256, 0, stream>>>(mem, 512, 512, WB_memn); // mem [256,512] as [N,K]

    // ---- embedding + memory bank ----
    embed_k<<<NTOK, 256, 0, stream>>>(ids, embed_w, X0, X0B);
    gemm(X0B, 512, WB_memn, EN, 256, nullptr, 0, nullptr, nullptr, 0, 1.f, 256, 512, 0);
    smrows_k<<<NTOK, 256, 0, stream>>>(EN, ENB);
    gemm(ENB, 256, WB_memt, RET, 512, nullptr, 0, nullptr, nullptr, 0, 1.f, 512, 256, 0);
    concat_bf_k<<<4096, 256, 0, stream>>>(X0, RET, XCATB);
    gemm(XCATB, 1024, WB_mp, X0, 512, X0B, 512, mp_b, nullptr, 0, 1.f, 512, 1024, 0);

    float* xcur = X0;
    float* xalt = X1;
    __bf16* xcurB = X0B;
    __bf16* xaltB = X1B;
    for (int l = 0; l < 2; ++l) {
        for (int p = 0; p < 2; ++p) {
            const int lp = l * 2 + p;
            const float* hptr = (p == 0) ? xcur : OUTS;
            const __bf16* hptrB = (p == 0) ? xcurB : OUTSB;
            const int hlda = (p == 0) ? 512 : 1024;
            gemm(hptrB, hlda, WB_qkv + (long)lp * 1536 * 512, QKV, 1536, nullptr, 0,
                 qkv_b + (long)lp * 1536, nullptr, 0, 1.f, 1536, 512, 0);
            meanp_k<<<256, 64, 0, stream>>>(hptr, hlda, PART);
            meanr_k<<<4, 256, 0, stream>>>(PART, HMEAN);
            aware_k<<<1, 64, 0, stream>>>(HMEAN, aw_w, aw_b, lp, AWARE);
            qkvprep_k<<<256, 256, 0, stream>>>(QKV, dscale, lp, AWARE, QKB, KB, VTB);
            attn2_k<<<512, 256, 0, stream>>>(QKB, KB, VTB, PRIORB,
                                             (p == 1) ? 1 : 0, OUTS, OUTSB, p * CDIM);
        }
        gemm(OUTSB, 1024, WB_mg + (long)l * 512 * 1024, Z, 512, nullptr, 0,
             mg_b + (long)l * 512, xcur, 512, 1.f, 512, 1024, 0);
        ln_k<<<NTOK, 256, 0, stream>>>(Z, ln_g + (long)l * 512, ln_b + (long)l * 512, XN, XNB);
        gate_k<<<NTOK, 64, 0, stream>>>(XN, gw, gb, l, WV, EIDX);
        route_k<<<1, 256, 0, stream>>>(EIDX, OFFI, LIST, POSMAP);
        moe_g1_k<<<dim3(8, 40), 256, 0, stream>>>(XNB, WB_e1 + (long)l * 8 * 524288,
                eb1 + (long)l * 8192, OFFI, LIST, EHB);
        moe_g2_k<<<dim3(4, 40), 256, 0, stream>>>(EHB, WB_e2 + (long)l * 8 * 524288,
                eb2 + (long)l * 4096, OFFI, EYS);
        reason2_k<<<4096, 256, 0, stream>>>(XN, EYS, WV, POSMAP, REASON);
        gemm(xcurB, 512, WB_q1 + (long)l * 2048 * 512, nullptr, 0, Q1BB, 2048,
             q1b + (long)l * 2048, nullptr, 0, 1.f, 2048, 512, 1);
        qual_k<<<NTOK, 256, 0, stream>>>(Q1BB, q2w, q2b, l, QUAL);
        xq_k<<<4096, 256, 0, stream>>>(xcur, QUAL, XQB);
        gemm(XQB, 512, WB_err + (long)l * 512 * 512, INTRO, 512, nullptr, 0,
             errb + (long)l * 512, xcur, 512, 0.3f, 512, 512, 0);
        concat_bf_k<<<4096, 256, 0, stream>>>(REASON, INTRO, XCATB);
        gemm(XCATB, 1024, WB_ag1, nullptr, 0, Q1BB, 2048, ag1b, nullptr, 0, 1.f, 2048, 1024, 1);
        gemm(Q1BB, 2048, WB_ag2, GATEB, 512, nullptr, 0, ag2b, nullptr, 0, 1.f, 512, 2048, 2);
        final_k<<<4096, 256, 0, stream>>>(REASON, GATEB, pscale, INTRO, xalt, xaltB);
        float* tmp = xcur; xcur = xalt; xalt = tmp;
        __bf16* tmpb = xcurB; xcurB = xaltB; xaltB = tmpb;
    }
    // ---- head ----
    gemm(xcurB, 512, WB_head, out, VDIM, nullptr, 0, head_b, nullptr, 0, 1.f, VDIM, 512, 0);
}